// Round 8
// baseline (287.687 us; speedup 1.0000x reference)
//
#include <hip/hip_runtime.h>
#include <hip/hip_bf16.h>
#include <stdint.h>
#include <cmath>

using bf16 = __hip_bfloat16;
typedef __attribute__((ext_vector_type(8))) short bf16x8;
typedef __attribute__((ext_vector_type(4))) short bf16x4;
typedef __attribute__((ext_vector_type(4))) float f32x4;

#define MFMA16(a, b, c) __builtin_amdgcn_mfma_f32_16x16x32_bf16(a, b, c, 0, 0, 0)

#if defined(__has_builtin)
#if __has_builtin(__builtin_amdgcn_mfma_f32_16x16x16bf16_1k)
#define HAVE_MFMA_K16 1
#endif
#if __has_builtin(__builtin_amdgcn_exp2f)
#define EXP2F __builtin_amdgcn_exp2f
#endif
#endif
#ifndef HAVE_MFMA_K16
#define HAVE_MFMA_K16 0
#endif
#ifndef EXP2F
#define EXP2F exp2f
#endif

#define NEG_BIG (-1e30f)
#define K2SCALE 0.18033688011112042f  /* 0.125 * log2(e) */

__device__ __forceinline__ short f2bf(float v) {
  return __builtin_bit_cast(short, __float2bfloat16(v));
}

// K=16 bf16 MFMA (A,B = 4 bf16/lane). Fallback: zero-padded K=32.
__device__ __forceinline__ f32x4 pv_mfma(bf16x4 va, bf16x4 pb, f32x4 c) {
#if HAVE_MFMA_K16
  return __builtin_amdgcn_mfma_f32_16x16x16bf16_1k(va, pb, c, 0, 0, 0);
#else
  const bf16x8 a = {va[0], va[1], va[2], va[3], 0, 0, 0, 0};
  const bf16x8 b = {pb[0], pb[1], pb[2], pb[3], 0, 0, 0, 0};
  return MFMA16(a, b, c);
#endif
}

// async global->LDS, 16B per lane. LDS dest = wave-uniform base + lane*16.
__device__ __forceinline__ void async_ld16(const bf16* g, bf16* l) {
  __builtin_amdgcn_global_load_lds(
      (const __attribute__((address_space(1))) unsigned int*)g,
      (__attribute__((address_space(3))) unsigned int*)l, 16, 0, 0);
}

template <typename T> __device__ __forceinline__ T cvt_out(float v);
template <> __device__ __forceinline__ float cvt_out<float>(float v) { return v; }
template <> __device__ __forceinline__ bf16 cvt_out<bf16>(float v) { return __float2bfloat16(v); }

// ---------------------------------------------------------------------------
// prep: one dispatch = x f32->bf16 convert + all four weight transposes.
// ---------------------------------------------------------------------------
__global__ void prep(const float* __restrict__ x,
                     const float* __restrict__ Wq, const float* __restrict__ Wk,
                     const float* __restrict__ Wv, const float* __restrict__ Wo,
                     bf16* __restrict__ xb, bf16* __restrict__ tq,
                     bf16* __restrict__ tk, bf16* __restrict__ tv,
                     bf16* __restrict__ to_) {
  __shared__ bf16 tile[32][33];
  const int bid = blockIdx.x;
  if (bid < 8192) {
    const int z = bid >> 11, tt = bid & 2047;
    const float* in = z == 0 ? Wq : z == 1 ? Wk : z == 2 ? Wv : Wo;
    bf16* out = z == 0 ? tq : z == 1 ? tk : z == 2 ? tv : to_;
    int R, Cc, c0, r0;
    if (z < 3) { R = 1024; Cc = 2048; c0 = (tt & 63) * 32; r0 = (tt >> 6) * 32; }
    else       { R = 2048; Cc = 1024; c0 = (tt & 31) * 32; r0 = (tt >> 5) * 32; }
    const int xx = threadIdx.x & 31;
    const int y = threadIdx.x >> 5;
#pragma unroll
    for (int yy = y; yy < 32; yy += 8)
      tile[yy][xx] = __float2bfloat16(in[(size_t)(r0 + yy) * Cc + c0 + xx]);
    __syncthreads();
#pragma unroll
    for (int yy = y; yy < 32; yy += 8)
      out[(size_t)(c0 + yy) * R + r0 + xx] = tile[xx][yy];
  } else {
    const int i = (bid - 8192) * 256 + threadIdx.x;  // < 1<<20 float4s
    const float4 v = ((const float4*)x)[i];
    bf16 o[4] = {__float2bfloat16(v.x), __float2bfloat16(v.y),
                 __float2bfloat16(v.z), __float2bfloat16(v.w)};
    *(uint64_t*)&xb[i * 4] = *(const uint64_t*)o;
  }
}

// ---------------------------------------------------------------------------
// Fused QKV projection: one dispatch, grid (512, 3).
// op=0: Q = xb @ WqT -> (b,h,n,d); op=1: K; op=2: V^T = wv @ xb^T -> (b,h,d,n)
// ---------------------------------------------------------------------------
__global__ __launch_bounds__(256)
void gemm_qkv(const bf16* __restrict__ xb, const bf16* __restrict__ wq,
              const bf16* __restrict__ wk, const bf16* __restrict__ wv,
              bf16* __restrict__ qo, bf16* __restrict__ ko, bf16* __restrict__ vo) {
  __shared__ __align__(16) bf16 As[128 * 32];
  __shared__ __align__(16) bf16 Bs[128 * 32];
  const int op = blockIdx.y;
  const int bid = blockIdx.x;
  const bf16 *A, *B;
  int m0, n0;
  if (op < 2) { A = xb; B = op ? wk : wq; m0 = (bid >> 4) * 128; n0 = (bid & 15) * 128; }
  else        { A = wv; B = xb;           m0 = (bid & 15) * 128; n0 = (bid >> 4) * 128; }
  const int K = 1024;

  const int t = threadIdx.x;
  const int l = t & 63, w = t >> 6;
  const int q4 = l >> 4, li = l & 15;
  const int wr = (w >> 1) * 64, wc = (w & 1) * 64;

  f32x4 acc[4][4] = {};
  const int colst = (t & 3) * 8;
  const bf16* gA = A + (size_t)m0 * K;
  const bf16* gB = B + (size_t)n0 * K;

  for (int k0 = 0; k0 < K; k0 += 32) {
#pragma unroll
    for (int p = 0; p < 2; ++p) {
      const int row = p * 64 + (t >> 2);
      const int lbase = p * 2048 + (t & ~63) * 8;
      async_ld16(gA + (size_t)row * K + k0 + colst, &As[lbase]);
      async_ld16(gB + (size_t)row * K + k0 + colst, &Bs[lbase]);
    }
    __syncthreads();
    bf16x8 af[4], bfr[4];
#pragma unroll
    for (int i = 0; i < 4; ++i)
      af[i] = *(const bf16x8*)&As[(wr + i * 16 + li) * 32 + q4 * 8];
#pragma unroll
    for (int j = 0; j < 4; ++j)
      bfr[j] = *(const bf16x8*)&Bs[(wc + j * 16 + li) * 32 + q4 * 8];
#pragma unroll
    for (int i = 0; i < 4; ++i)
#pragma unroll
      for (int j = 0; j < 4; ++j)
        acc[i][j] = MFMA16(af[i], bfr[j], acc[i][j]);
    __syncthreads();
  }

#pragma unroll
  for (int i = 0; i < 4; ++i)
#pragma unroll
    for (int j = 0; j < 4; ++j)
#pragma unroll
      for (int r = 0; r < 4; ++r) {
        const int gm = m0 + wr + i * 16 + q4 * 4 + r;
        const int gn = n0 + wc + j * 16 + li;
        const bf16 v = __float2bfloat16(acc[i][j][r]);
        if (op < 2) {
          const int b = gm >> 11, nn = gm & 2047;
          const int h = gn >> 7, d = gn & 127;
          (op ? ko : qo)[((size_t)(b * 16 + h) * 2048 + nn) * 128 + d] = v;
        } else {
          const int h = gm >> 7, d = gm & 127;
          const int b = gn >> 11, nn = gn & 2047;
          vo[((size_t)(b * 16 + h) * 128 + d) * 2048 + nn] = v;
        }
      }
}

// ---------------------------------------------------------------------------
// GEMM-BT (final projection): C[m][n] = sum_k A[m][k]*B[n][k], C row-major f32.
// ---------------------------------------------------------------------------
template <int NT, typename OT>
__global__ __launch_bounds__(256)
void gemm_bt(const bf16* __restrict__ A, const bf16* __restrict__ B,
             OT* __restrict__ C, int M, int N, int K) {
  __shared__ __align__(16) bf16 As[128 * 32];
  __shared__ __align__(16) bf16 Bs[NT * 32];
  constexpr int JN = NT / 32;
  const int t = threadIdx.x;
  const int l = t & 63, w = t >> 6;
  const int q4 = l >> 4, li = l & 15;
  const int m0 = blockIdx.y * 128;
  const int n0 = blockIdx.x * NT;
  const int wr = (w >> 1) * 64, wc = (w & 1) * (NT / 2);

  f32x4 acc[4][JN] = {};
  const int colst = (t & 3) * 8;
  const bf16* gA = A + (size_t)m0 * K;
  const bf16* gB = B + (size_t)n0 * K;

  for (int k0 = 0; k0 < K; k0 += 32) {
#pragma unroll
    for (int p = 0; p < 2; ++p) {
      const int row = p * 64 + (t >> 2);
      const int lbase = p * 2048 + (t & ~63) * 8;
      async_ld16(gA + (size_t)row * K + k0 + colst, &As[lbase]);
    }
#pragma unroll
    for (int p = 0; p < NT / 64; ++p) {
      const int row = p * 64 + (t >> 2);
      const int lbase = p * 2048 + (t & ~63) * 8;
      async_ld16(gB + (size_t)row * K + k0 + colst, &Bs[lbase]);
    }
    __syncthreads();
    bf16x8 af[4], bfr[JN];
#pragma unroll
    for (int i = 0; i < 4; ++i)
      af[i] = *(const bf16x8*)&As[(wr + i * 16 + li) * 32 + q4 * 8];
#pragma unroll
    for (int j = 0; j < JN; ++j)
      bfr[j] = *(const bf16x8*)&Bs[(wc + j * 16 + li) * 32 + q4 * 8];
#pragma unroll
    for (int i = 0; i < 4; ++i)
#pragma unroll
      for (int j = 0; j < JN; ++j)
        acc[i][j] = MFMA16(af[i], bfr[j], acc[i][j]);
    __syncthreads();
  }

#pragma unroll
  for (int i = 0; i < 4; ++i)
#pragma unroll
    for (int j = 0; j < JN; ++j)
#pragma unroll
      for (int r = 0; r < 4; ++r) {
        const int gm = m0 + wr + i * 16 + q4 * 4 + r;
        const int gn = n0 + wc + j * 16 + li;
        C[(size_t)gm * N + gn] = cvt_out<OT>(acc[i][j][r]);
      }
}

// ---------------------------------------------------------------------------
// Causal flash attention, S^T formulation.
//
// v9 = v8 with the staging-stride bug fixed. v8's NaN: with 512 threads a
// DMA round covers 512*16B = 4096 elems, but the round offset was written
// as p*8192 — round 1 landed past the end of Ks (clobbering Vts) and past
// Vts entirely; K rows 32-63 / V rows 64-127 were never staged (garbage
// LDS decodes as NaN bf16). Invariant (verified against v6: 256thr/p*2048,
// v7: 128thr/p*1024): round_stride = threads*8 elems -> p*4096 here.
//
// Key-split waves (the TLP experiment): block = 512 thr = 8 waves =
// 4 qgroups (16 q each) x 2 key-halves over QT=64/KT=64. Each wave runs an
// independent online (m,l,O) over its disjoint 32-key half-sequences;
// merged once at block end via LDS (a_i = exp2((m_i-m*)*K2); skipped
// waves have m=-1e30 -> a=0 exactly). Aggregate MFMA/VALU/LDS demand
// identical to v6; total waves double to 8192 (target 24-32/CU).
// Keeps: source-XOR swizzle staging, fused exp2 softmax on raw scores,
// wave-uniform rescale skip, long-first dispatch, diagonal-only masking.
// ---------------------------------------------------------------------------
__global__ __launch_bounds__(512, 2)
void flash_attn(const bf16* __restrict__ qm, const bf16* __restrict__ km,
                const bf16* __restrict__ vtm, bf16* __restrict__ om) {
  __shared__ __align__(16) bf16 Ks[64 * 128];   // [key][d]
  __shared__ __align__(16) bf16 Vts[128 * 64];  // [d][key]

  const int t = threadIdx.x;         // 0..511
  const int l = t & 63, w = t >> 6;  // 8 waves
  const int qg = w & 3, kh = w >> 2; // qgroup, key-half
  const int q4 = l >> 4, li = l & 15;
  const int bh = blockIdx.x;
  const int y = blockIdx.y;
  const int qt = (y < 16) ? 31 - y : y - 16;  // long blocks dispatch first
  const int qs = qt * 64;
  const size_t qkbase = (size_t)bh * 2048 * 128;
  const size_t vbase = (size_t)bh * 128 * 2048;
  const int b = bh >> 4, h = bh & 15;

  // Q fragments (B operand of S^T): 16 queries qs + qg*16 + li
  bf16x8 qf[4];
  {
    const bf16* Qb = qm + qkbase + (size_t)(qs + qg * 16 + li) * 128;
#pragma unroll
    for (int f = 0; f < 4; ++f)
      qf[f] = *(const bf16x8*)(Qb + f * 32 + q4 * 8);
  }

  f32x4 O[8] = {};
  float mrun = NEG_BIG, lrun = 0.f;
  const int gmq = qs + qg * 16 + li;   // this lane's query index
  const int gmqmax = qs + qg * 16 + 15;
  const int kh32 = kh * 32;            // key offset of my half within a tile

  // staging address components (512 threads; 2 rounds per K and V tile;
  // round stride = 512 thr * 8 elems = 4096)
  const int ksrow = t >> 4;              // K: 0..31
  const int kchu = t & 15;
  const int vsrow = t >> 3;              // V: 0..63
  const int vchu = t & 7;
  const int dstbase = (t & ~63) * 8;     // wave-uniform LDS base (elems)

  const int nt = qt + 1;  // number of 64-key tiles

  for (int j = 0; j < nt; ++j) {
    const int kb = j * 64;
    // stage K (64x128) and Vt (128x64), source-XOR swizzled, linear LDS dest.
#pragma unroll
    for (int p = 0; p < 2; ++p) {
      const int kr = p * 32 + ksrow;
      async_ld16(km + qkbase + (size_t)(kb + kr) * 128 + (size_t)((kchu ^ (kr & 7)) * 8),
                 &Ks[p * 4096 + dstbase]);
      const int vr = p * 64 + vsrow;
      async_ld16(vtm + vbase + (size_t)vr * 2048 + kb + (size_t)((vchu ^ (vr & 7)) * 8),
                 &Vts[p * 4096 + dstbase]);
    }
    __syncthreads();

    // fully-masked half-tile for this wave? (smallest key > largest query)
    if (kb + kh32 <= gmqmax) {
      const bool msk = (j == qt);  // only the diagonal tile masks

      // S^T = K Q^T over my 32-key half: S[kc] reg r = score(key kb+kh32+kc*16+q4*4+r, q li)
      f32x4 S[2];
#pragma unroll
      for (int kc = 0; kc < 2; ++kc) {
        const int krow = kh32 + kc * 16 + li;
        bf16x8 kf[4];
#pragma unroll
        for (int f = 0; f < 4; ++f)
          kf[f] = *(const bf16x8*)&Ks[krow * 128 + (((f * 4 + q4) ^ (li & 7)) * 8)];
        f32x4 s = {0.f, 0.f, 0.f, 0.f};
#pragma unroll
        for (int f = 0; f < 4; ++f) s = MFMA16(kf[f], qf[f], s);
        S[kc] = s;
      }

      if (msk) {
#pragma unroll
        for (int kc = 0; kc < 2; ++kc)
#pragma unroll
          for (int r = 0; r < 4; ++r)
            if ((kb + kh32 + kc * 16 + q4 * 4 + r) > gmq) S[kc][r] = NEG_BIG;
      }

      // online softmax on raw scores (8 values/lane)
      float mx = fmaxf(fmaxf(fmaxf(S[0][0], S[0][1]), fmaxf(S[0][2], S[0][3])),
                       fmaxf(fmaxf(S[1][0], S[1][1]), fmaxf(S[1][2], S[1][3])));
      mx = fmaxf(mx, __shfl_xor(mx, 16));
      mx = fmaxf(mx, __shfl_xor(mx, 32));
      const float mold = mrun;
      const float nm = fmaxf(mrun, mx);
      const bool nomove = (mx <= mold);
      mrun = nm;
      const float nmk = nm * K2SCALE;

      bf16x4 pb[2];
      float rs = 0.f;
#pragma unroll
      for (int kc = 0; kc < 2; ++kc) {
        float e[4];
#pragma unroll
        for (int r = 0; r < 4; ++r) {
          e[r] = EXP2F(__builtin_fmaf(S[kc][r], K2SCALE, -nmk));
          pb[kc][r] = f2bf(e[r]);
        }
        rs += (e[0] + e[1]) + (e[2] + e[3]);
      }
      rs += __shfl_xor(rs, 16);
      rs += __shfl_xor(rs, 32);

      if (__all(nomove)) {  // no lane's max moved: alpha == 1 everywhere
        lrun += rs;
      } else {
        const float alpha = EXP2F((mold - nm) * K2SCALE);
        lrun = lrun * alpha + rs;
#pragma unroll
        for (int dt = 0; dt < 8; ++dt) O[dt] *= alpha;
      }

      // O^T += V^T P^T over my 32-key half
#pragma unroll
      for (int dt = 0; dt < 8; ++dt)
#pragma unroll
        for (int kc = 0; kc < 2; ++kc) {
          const int gc = kh * 4 + kc * 2 + (q4 >> 1);  // 8-key chunk in 64-key row
          const bf16x4 va = *(const bf16x4*)&Vts[(dt * 16 + li) * 64 +
                                                 ((gc ^ (li & 7)) * 8) +
                                                 (q4 & 1) * 4];
          O[dt] = pv_mfma(va, pb[kc], O[dt]);
        }
    }
    __syncthreads();
  }

  // ---- cross-kh merge via LDS (Ks/Vts dead now) ----
  // mex: [kh][qg*64+l] m values (2KB in Vts); lex: a1*l1 (1KB in Vts);
  // oex: [qg*64+l][16] f32 chunk (16KB = all of Ks), used twice.
  float* mex = (float*)Vts;
  float* lex = (float*)Vts + 512;
  float* oex = (float*)Ks;
  const int idx = qg * 64 + l;

  mex[kh * 256 + idx] = mrun;
  __syncthreads();
  const float mo = mex[(kh ^ 1) * 256 + idx];
  const float ms = fmaxf(mrun, mo);
  const float al = EXP2F((mrun - ms) * K2SCALE);  // my rescale to merged max

  if (kh) {
    lex[idx] = al * lrun;
#pragma unroll
    for (int dt = 0; dt < 4; ++dt) *(f32x4*)&oex[idx * 16 + dt * 4] = O[dt] * al;
  }
  __syncthreads();
  if (!kh) {
    lrun = al * lrun + lex[idx];
#pragma unroll
    for (int dt = 0; dt < 4; ++dt) {
      const f32x4 o1 = *(const f32x4*)&oex[idx * 16 + dt * 4];
      O[dt] = O[dt] * al + o1;
    }
  }
  __syncthreads();
  if (kh) {
#pragma unroll
    for (int dt = 0; dt < 4; ++dt) *(f32x4*)&oex[idx * 16 + dt * 4] = O[dt + 4] * al;
  }
  __syncthreads();
  if (!kh) {
#pragma unroll
    for (int dt = 0; dt < 4; ++dt) {
      const f32x4 o1 = *(const f32x4*)&oex[idx * 16 + dt * 4];
      O[dt + 4] = O[dt + 4] * al + o1;
    }
    // epilogue: normalize, write om[query][h*128+d], d = dt*16+q4*4+r
    const float inv = 1.0f / lrun;
    const size_t orow = (size_t)(b * 2048 + qs + qg * 16 + li) * 2048 + h * 128;
#pragma unroll
    for (int dt = 0; dt < 8; ++dt) {
      bf16x4 o4;
#pragma unroll
      for (int r = 0; r < 4; ++r) o4[r] = f2bf(O[dt][r] * inv);
      *(bf16x4*)&om[orow + dt * 16 + q4 * 4] = o4;
    }
  }
}

// ---------------------------------------------------------------------------
extern "C" void kernel_launch(void* const* d_in, const int* in_sizes, int n_in,
                              void* d_out, int out_size, void* d_ws, size_t ws_size,
                              hipStream_t stream) {
  const float* x = (const float*)d_in[0];
  const float* Wq = (const float*)d_in[1];
  const float* Wk = (const float*)d_in[2];
  const float* Wv = (const float*)d_in[3];
  const float* Wo = (const float*)d_in[4];
  float* out = (float*)d_out;

  // Workspace (bf16 elems), 36M = 72 MB:
  //   [0,4M) xb | [4M,6M) wTq | [6M,8M) wTk | [8M,10M) wTv | [10M,12M) woT
  //   [12M,20M) q_ws | [20M,28M) k_ws | [28M,36M) vt_ws
  //   at_ws = [2M,10M) (aliases xb-upper + wTq/k/v; dead before flash writes)
  bf16* ws = (bf16*)d_ws;
  const size_t MEG = 1u << 20;
  bf16* xb = ws;
  bf16* wTq = ws + 4 * MEG;
  bf16* wTk = ws + 6 * MEG;
  bf16* wTv = ws + 8 * MEG;
  bf16* woT = ws + 10 * MEG;
  bf16* at_ws = ws + 2 * MEG;
  bf16* q_ws = ws + 12 * MEG;
  bf16* k_ws = ws + 20 * MEG;
  bf16* vt_ws = ws + 28 * MEG;

  const dim3 blk(256);

  prep<<<dim3(12288), blk, 0, stream>>>(x, Wq, Wk, Wv, Wo, xb, wTq, wTk, wTv, woT);
  gemm_qkv<<<dim3(512, 3), blk, 0, stream>>>(xb, wTq, wTk, wTv, q_ws, k_ws, vt_ws);
  flash_attn<<<dim3(32, 32), dim3(512), 0, stream>>>(q_ws, k_ws, vt_ws, at_ws);
  gemm_bt<64, float><<<dim3(16, 32), blk, 0, stream>>>(at_ws, woT, out, 4096, 1024, 2048);
}

// Round 9
// 273.771 us; speedup vs baseline: 1.0508x; 1.0508x over previous
//
#include <hip/hip_runtime.h>
#include <hip/hip_bf16.h>
#include <stdint.h>
#include <cmath>

using bf16 = __hip_bfloat16;
typedef __attribute__((ext_vector_type(8))) short bf16x8;
typedef __attribute__((ext_vector_type(4))) short bf16x4;
typedef __attribute__((ext_vector_type(4))) float f32x4;

#define MFMA16(a, b, c) __builtin_amdgcn_mfma_f32_16x16x32_bf16(a, b, c, 0, 0, 0)

#if defined(__has_builtin)
#if __has_builtin(__builtin_amdgcn_mfma_f32_16x16x16bf16_1k)
#define HAVE_MFMA_K16 1
#endif
#if __has_builtin(__builtin_amdgcn_exp2f)
#define EXP2F __builtin_amdgcn_exp2f
#endif
#endif
#ifndef HAVE_MFMA_K16
#define HAVE_MFMA_K16 0
#endif
#ifndef EXP2F
#define EXP2F exp2f
#endif

#define NEG_BIG (-1e30f)
#define K2SCALE 0.18033688011112042f  /* 0.125 * log2(e) */

__device__ __forceinline__ short f2bf(float v) {
  return __builtin_bit_cast(short, __float2bfloat16(v));
}

// K=16 bf16 MFMA (A,B = 4 bf16/lane). Fallback: zero-padded K=32.
__device__ __forceinline__ f32x4 pv_mfma(bf16x4 va, bf16x4 pb, f32x4 c) {
#if HAVE_MFMA_K16
  return __builtin_amdgcn_mfma_f32_16x16x16bf16_1k(va, pb, c, 0, 0, 0);
#else
  const bf16x8 a = {va[0], va[1], va[2], va[3], 0, 0, 0, 0};
  const bf16x8 b = {pb[0], pb[1], pb[2], pb[3], 0, 0, 0, 0};
  return MFMA16(a, b, c);
#endif
}

// async global->LDS, 16B per lane. LDS dest = wave-uniform base + lane*16.
__device__ __forceinline__ void async_ld16(const bf16* g, bf16* l) {
  __builtin_amdgcn_global_load_lds(
      (const __attribute__((address_space(1))) unsigned int*)g,
      (__attribute__((address_space(3))) unsigned int*)l, 16, 0, 0);
}

template <typename T> __device__ __forceinline__ T cvt_out(float v);
template <> __device__ __forceinline__ float cvt_out<float>(float v) { return v; }
template <> __device__ __forceinline__ bf16 cvt_out<bf16>(float v) { return __float2bfloat16(v); }

// ---------------------------------------------------------------------------
// prep: one dispatch = x f32->bf16 convert + all four weight transposes.
// ---------------------------------------------------------------------------
__global__ void prep(const float* __restrict__ x,
                     const float* __restrict__ Wq, const float* __restrict__ Wk,
                     const float* __restrict__ Wv, const float* __restrict__ Wo,
                     bf16* __restrict__ xb, bf16* __restrict__ tq,
                     bf16* __restrict__ tk, bf16* __restrict__ tv,
                     bf16* __restrict__ to_) {
  __shared__ bf16 tile[32][33];
  const int bid = blockIdx.x;
  if (bid < 8192) {
    const int z = bid >> 11, tt = bid & 2047;
    const float* in = z == 0 ? Wq : z == 1 ? Wk : z == 2 ? Wv : Wo;
    bf16* out = z == 0 ? tq : z == 1 ? tk : z == 2 ? tv : to_;
    int R, Cc, c0, r0;
    if (z < 3) { R = 1024; Cc = 2048; c0 = (tt & 63) * 32; r0 = (tt >> 6) * 32; }
    else       { R = 2048; Cc = 1024; c0 = (tt & 31) * 32; r0 = (tt >> 5) * 32; }
    const int xx = threadIdx.x & 31;
    const int y = threadIdx.x >> 5;
#pragma unroll
    for (int yy = y; yy < 32; yy += 8)
      tile[yy][xx] = __float2bfloat16(in[(size_t)(r0 + yy) * Cc + c0 + xx]);
    __syncthreads();
#pragma unroll
    for (int yy = y; yy < 32; yy += 8)
      out[(size_t)(c0 + yy) * R + r0 + xx] = tile[xx][yy];
  } else {
    const int i = (bid - 8192) * 256 + threadIdx.x;  // < 1<<20 float4s
    const float4 v = ((const float4*)x)[i];
    bf16 o[4] = {__float2bfloat16(v.x), __float2bfloat16(v.y),
                 __float2bfloat16(v.z), __float2bfloat16(v.w)};
    *(uint64_t*)&xb[i * 4] = *(const uint64_t*)o;
  }
}

// ---------------------------------------------------------------------------
// Fused QKV projection: one dispatch, grid (512, 3).
// op=0: Q = xb @ WqT -> (b,h,n,d); op=1: K; op=2: V^T = wv @ xb^T -> (b,h,d,n)
// ---------------------------------------------------------------------------
__global__ __launch_bounds__(256)
void gemm_qkv(const bf16* __restrict__ xb, const bf16* __restrict__ wq,
              const bf16* __restrict__ wk, const bf16* __restrict__ wv,
              bf16* __restrict__ qo, bf16* __restrict__ ko, bf16* __restrict__ vo) {
  __shared__ __align__(16) bf16 As[128 * 32];
  __shared__ __align__(16) bf16 Bs[128 * 32];
  const int op = blockIdx.y;
  const int bid = blockIdx.x;
  const bf16 *A, *B;
  int m0, n0;
  if (op < 2) { A = xb; B = op ? wk : wq; m0 = (bid >> 4) * 128; n0 = (bid & 15) * 128; }
  else        { A = wv; B = xb;           m0 = (bid & 15) * 128; n0 = (bid >> 4) * 128; }
  const int K = 1024;

  const int t = threadIdx.x;
  const int l = t & 63, w = t >> 6;
  const int q4 = l >> 4, li = l & 15;
  const int wr = (w >> 1) * 64, wc = (w & 1) * 64;

  f32x4 acc[4][4] = {};
  const int colst = (t & 3) * 8;
  const bf16* gA = A + (size_t)m0 * K;
  const bf16* gB = B + (size_t)n0 * K;

  for (int k0 = 0; k0 < K; k0 += 32) {
#pragma unroll
    for (int p = 0; p < 2; ++p) {
      const int row = p * 64 + (t >> 2);
      const int lbase = p * 2048 + (t & ~63) * 8;
      async_ld16(gA + (size_t)row * K + k0 + colst, &As[lbase]);
      async_ld16(gB + (size_t)row * K + k0 + colst, &Bs[lbase]);
    }
    __syncthreads();
    bf16x8 af[4], bfr[4];
#pragma unroll
    for (int i = 0; i < 4; ++i)
      af[i] = *(const bf16x8*)&As[(wr + i * 16 + li) * 32 + q4 * 8];
#pragma unroll
    for (int j = 0; j < 4; ++j)
      bfr[j] = *(const bf16x8*)&Bs[(wc + j * 16 + li) * 32 + q4 * 8];
#pragma unroll
    for (int i = 0; i < 4; ++i)
#pragma unroll
      for (int j = 0; j < 4; ++j)
        acc[i][j] = MFMA16(af[i], bfr[j], acc[i][j]);
    __syncthreads();
  }

#pragma unroll
  for (int i = 0; i < 4; ++i)
#pragma unroll
    for (int j = 0; j < 4; ++j)
#pragma unroll
      for (int r = 0; r < 4; ++r) {
        const int gm = m0 + wr + i * 16 + q4 * 4 + r;
        const int gn = n0 + wc + j * 16 + li;
        const bf16 v = __float2bfloat16(acc[i][j][r]);
        if (op < 2) {
          const int b = gm >> 11, nn = gm & 2047;
          const int h = gn >> 7, d = gn & 127;
          (op ? ko : qo)[((size_t)(b * 16 + h) * 2048 + nn) * 128 + d] = v;
        } else {
          const int h = gm >> 7, d = gm & 127;
          const int b = gn >> 11, nn = gn & 2047;
          vo[((size_t)(b * 16 + h) * 128 + d) * 2048 + nn] = v;
        }
      }
}

// ---------------------------------------------------------------------------
// GEMM-BT (final projection): C[m][n] = sum_k A[m][k]*B[n][k], C row-major f32.
// NT=128 now (was 64): the 128x64 output tile wasted staging BW per MFMA
// (measured tile ladder: 64^2=343 TF, 128^2=912). NT=128 is byte-identical
// geometry to the proven gemm_qkv kernel; grid (8,32) = 256 blocks.
// ---------------------------------------------------------------------------
template <int NT, typename OT>
__global__ __launch_bounds__(256)
void gemm_bt(const bf16* __restrict__ A, const bf16* __restrict__ B,
             OT* __restrict__ C, int M, int N, int K) {
  __shared__ __align__(16) bf16 As[128 * 32];
  __shared__ __align__(16) bf16 Bs[NT * 32];
  constexpr int JN = NT / 32;
  const int t = threadIdx.x;
  const int l = t & 63, w = t >> 6;
  const int q4 = l >> 4, li = l & 15;
  const int m0 = blockIdx.y * 128;
  const int n0 = blockIdx.x * NT;
  const int wr = (w >> 1) * 64, wc = (w & 1) * (NT / 2);

  f32x4 acc[4][JN] = {};
  const int colst = (t & 3) * 8;
  const bf16* gA = A + (size_t)m0 * K;
  const bf16* gB = B + (size_t)n0 * K;

  for (int k0 = 0; k0 < K; k0 += 32) {
#pragma unroll
    for (int p = 0; p < 2; ++p) {
      const int row = p * 64 + (t >> 2);
      const int lbase = p * 2048 + (t & ~63) * 8;
      async_ld16(gA + (size_t)row * K + k0 + colst, &As[lbase]);
    }
#pragma unroll
    for (int p = 0; p < NT / 64; ++p) {
      const int row = p * 64 + (t >> 2);
      const int lbase = p * 2048 + (t & ~63) * 8;
      async_ld16(gB + (size_t)row * K + k0 + colst, &Bs[lbase]);
    }
    __syncthreads();
    bf16x8 af[4], bfr[JN];
#pragma unroll
    for (int i = 0; i < 4; ++i)
      af[i] = *(const bf16x8*)&As[(wr + i * 16 + li) * 32 + q4 * 8];
#pragma unroll
    for (int j = 0; j < JN; ++j)
      bfr[j] = *(const bf16x8*)&Bs[(wc + j * 16 + li) * 32 + q4 * 8];
#pragma unroll
    for (int i = 0; i < 4; ++i)
#pragma unroll
      for (int j = 0; j < JN; ++j)
        acc[i][j] = MFMA16(af[i], bfr[j], acc[i][j]);
    __syncthreads();
  }

#pragma unroll
  for (int i = 0; i < 4; ++i)
#pragma unroll
    for (int j = 0; j < JN; ++j)
#pragma unroll
      for (int r = 0; r < 4; ++r) {
        const int gm = m0 + wr + i * 16 + q4 * 4 + r;
        const int gn = n0 + wc + j * 16 + li;
        C[(size_t)gm * N + gn] = cvt_out<OT>(acc[i][j][r]);
      }
}

// ---------------------------------------------------------------------------
// Causal flash attention, S^T formulation.
//
// v10 = exact v6 (session-best flash, 79.6us e2e 268.6) + T5 s_setprio
// around the QK and PV MFMA clusters. Post-mortems of rounds 1/5/8: TLP is
// NOT the lever (occupancy 13->26->31% gave 84->79.6->101us); v6's regime —
// 4 independent blocks/CU at uncorrelated phases — is the m191 attn regime
// where setprio(1) around MFMA measured +4-7% (and worst case -1.5%).
// Geometry: QT=64 (16q/wave), grid (32,32)=1024 blocks, K+V in LDS
// (64-key single-buffered, 16KB+16KB), launch_bounds(256,2), VGPR ~72.
// Keeps: source-XOR swizzle staging, fused exp2 softmax on raw scores,
// wave-uniform rescale skip, long-first dispatch, diagonal-only masking.
// ---------------------------------------------------------------------------
__global__ __launch_bounds__(256, 2)
void flash_attn(const bf16* __restrict__ qm, const bf16* __restrict__ km,
                const bf16* __restrict__ vtm, bf16* __restrict__ om) {
  __shared__ __align__(16) bf16 Ks[64 * 128];   // [key][d]
  __shared__ __align__(16) bf16 Vts[128 * 64];  // [d][key]

  const int t = threadIdx.x;
  const int l = t & 63, w = t >> 6;
  const int q4 = l >> 4, li = l & 15;
  const int bh = blockIdx.x;
  const int y = blockIdx.y;
  const int qt = (y < 16) ? 31 - y : y - 16;  // long blocks dispatch first
  const int qs = qt * 64;
  const size_t qkbase = (size_t)bh * 2048 * 128;
  const size_t vbase = (size_t)bh * 128 * 2048;
  const int b = bh >> 4, h = bh & 15;

  // Q fragments (B operand of S^T), 16 queries for this wave
  bf16x8 qf[4];
  {
    const bf16* Qb = qm + qkbase + (size_t)(qs + w * 16 + li) * 128;
#pragma unroll
    for (int f = 0; f < 4; ++f)
      qf[f] = *(const bf16x8*)(Qb + f * 32 + q4 * 8);
  }

  f32x4 O[8] = {};
  float mrun = NEG_BIG, lrun = 0.f;
  const int gmq = qs + w * 16 + li;  // this lane's query index

  // staging address components (per lane, constant across tiles)
  const int ksrow = t >> 4;            // K: row within 16-row group
  const int kchu = t & 15;             // K: chunk (16 per 128-elem row)
  const int vsrow = t >> 3;            // V: row within 32-row group
  const int vchu = t & 7;              // V: chunk (8 per 64-elem row)
  const int wavebase = (t & ~63) * 8;  // LDS elems, wave-uniform

  const int nt = qt + 1;  // number of 64-key tiles

  for (int j = 0; j < nt; ++j) {
    const int kb = j * 64;
    // stage K (64 keys x 128 d) and Vt (128 d x 64 keys) via async DMA,
    // source-swizzled: lane loads global chunk (chu)^(row&7), lands at
    // linear LDS position (row, chu).
#pragma unroll
    for (int p = 0; p < 4; ++p) {
      const int kr = p * 16 + ksrow;
      async_ld16(km + qkbase + (size_t)(kb + kr) * 128 + (size_t)((kchu ^ (kr & 7)) * 8),
                 &Ks[p * 2048 + wavebase]);
      const int vr = p * 32 + vsrow;
      async_ld16(vtm + vbase + (size_t)vr * 2048 + kb + (size_t)((vchu ^ (vr & 7)) * 8),
                 &Vts[p * 2048 + wavebase]);
    }
    __syncthreads();

    const bool msk = (j == qt);  // only the diagonal tile masks

    // S^T = K Q^T : S[jk] reg r = raw score(key = kb+jk*16+q4*4+r, query li)
    f32x4 S[4];
    __builtin_amdgcn_s_setprio(1);
#pragma unroll
    for (int jk = 0; jk < 4; ++jk) {
      const int krow = jk * 16 + li;
      bf16x8 kf[4];
#pragma unroll
      for (int f = 0; f < 4; ++f)
        kf[f] = *(const bf16x8*)&Ks[krow * 128 + (((f * 4 + q4) ^ (li & 7)) * 8)];
      f32x4 s = {0.f, 0.f, 0.f, 0.f};
#pragma unroll
      for (int f = 0; f < 4; ++f) s = MFMA16(kf[f], qf[f], s);
      S[jk] = s;
    }
    __builtin_amdgcn_s_setprio(0);

    if (msk) {
#pragma unroll
      for (int jk = 0; jk < 4; ++jk)
#pragma unroll
        for (int r = 0; r < 4; ++r)
          if ((kb + jk * 16 + q4 * 4 + r) > gmq) S[jk][r] = NEG_BIG;
    }

    // online softmax on raw scores
    float mx = NEG_BIG;
#pragma unroll
    for (int jk = 0; jk < 4; ++jk)
      mx = fmaxf(mx, fmaxf(fmaxf(S[jk][0], S[jk][1]), fmaxf(S[jk][2], S[jk][3])));
    mx = fmaxf(mx, __shfl_xor(mx, 16));
    mx = fmaxf(mx, __shfl_xor(mx, 32));
    const float mold = mrun;
    const float nm = fmaxf(mrun, mx);
    const bool nomove = (mx <= mold);
    mrun = nm;
    const float nmk = nm * K2SCALE;

    bf16x4 pb[4];
    float rs = 0.f;
#pragma unroll
    for (int jk = 0; jk < 4; ++jk) {
      float e[4];
#pragma unroll
      for (int r = 0; r < 4; ++r) {
        e[r] = EXP2F(__builtin_fmaf(S[jk][r], K2SCALE, -nmk));
        pb[jk][r] = f2bf(e[r]);
      }
      rs += (e[0] + e[1]) + (e[2] + e[3]);
    }
    rs += __shfl_xor(rs, 16);
    rs += __shfl_xor(rs, 32);

    if (__all(nomove)) {  // no lane's max moved: alpha == 1 everywhere
      lrun += rs;
    } else {
      const float alpha = EXP2F((mold - nm) * K2SCALE);
      lrun = lrun * alpha + rs;
#pragma unroll
      for (int dt = 0; dt < 8; ++dt) O[dt] *= alpha;
    }

    // O^T += V^T P^T : V^T from LDS (swizzled layout)
    __builtin_amdgcn_s_setprio(1);
#pragma unroll
    for (int dt = 0; dt < 8; ++dt)
#pragma unroll
      for (int kc = 0; kc < 4; ++kc) {
        const int gc = kc * 2 + (q4 >> 1);  // key-chunk within 64-key tile
        const bf16x4 va = *(const bf16x4*)&Vts[(dt * 16 + li) * 64 +
                                               ((gc ^ (li & 7)) * 8) +
                                               (q4 & 1) * 4];
        O[dt] = pv_mfma(va, pb[kc], O[dt]);
      }
    __builtin_amdgcn_s_setprio(0);
    __syncthreads();
  }

  // epilogue: normalize, write om[query][h*128+d], d = dt*16+q4*4+r
  {
    const float inv = 1.0f / lrun;
    const size_t orow = (size_t)(b * 2048 + qs + w * 16 + li) * 2048 + h * 128;
#pragma unroll
    for (int dt = 0; dt < 8; ++dt) {
      bf16x4 o4;
#pragma unroll
      for (int r = 0; r < 4; ++r) o4[r] = f2bf(O[dt][r] * inv);
      *(bf16x4*)&om[orow + dt * 16 + q4 * 4] = o4;
    }
  }
}

// ---------------------------------------------------------------------------
extern "C" void kernel_launch(void* const* d_in, const int* in_sizes, int n_in,
                              void* d_out, int out_size, void* d_ws, size_t ws_size,
                              hipStream_t stream) {
  const float* x = (const float*)d_in[0];
  const float* Wq = (const float*)d_in[1];
  const float* Wk = (const float*)d_in[2];
  const float* Wv = (const float*)d_in[3];
  const float* Wo = (const float*)d_in[4];
  float* out = (float*)d_out;

  // Workspace (bf16 elems), 36M = 72 MB:
  //   [0,4M) xb | [4M,6M) wTq | [6M,8M) wTk | [8M,10M) wTv | [10M,12M) woT
  //   [12M,20M) q_ws | [20M,28M) k_ws | [28M,36M) vt_ws
  //   at_ws = [2M,10M) (aliases xb-upper + wTq/k/v; dead before flash writes)
  bf16* ws = (bf16*)d_ws;
  const size_t MEG = 1u << 20;
  bf16* xb = ws;
  bf16* wTq = ws + 4 * MEG;
  bf16* wTk = ws + 6 * MEG;
  bf16* wTv = ws + 8 * MEG;
  bf16* woT = ws + 10 * MEG;
  bf16* at_ws = ws + 2 * MEG;
  bf16* q_ws = ws + 12 * MEG;
  bf16* k_ws = ws + 20 * MEG;
  bf16* vt_ws = ws + 28 * MEG;

  const dim3 blk(256);

  prep<<<dim3(12288), blk, 0, stream>>>(x, Wq, Wk, Wv, Wo, xb, wTq, wTk, wTv, woT);
  gemm_qkv<<<dim3(512, 3), blk, 0, stream>>>(xb, wTq, wTk, wTv, q_ws, k_ws, vt_ws);
  flash_attn<<<dim3(32, 32), blk, 0, stream>>>(q_ws, k_ws, vt_ws, at_ws);
  gemm_bt<128, float><<<dim3(8, 32), blk, 0, stream>>>(at_ws, woT, out, 4096, 1024, 2048);
}

// Round 10
// 266.219 us; speedup vs baseline: 1.0806x; 1.0284x over previous
//
#include <hip/hip_runtime.h>
#include <hip/hip_bf16.h>
#include <stdint.h>
#include <cmath>

using bf16 = __hip_bfloat16;
typedef __attribute__((ext_vector_type(8))) short bf16x8;
typedef __attribute__((ext_vector_type(4))) short bf16x4;
typedef __attribute__((ext_vector_type(4))) float f32x4;

#define MFMA16(a, b, c) __builtin_amdgcn_mfma_f32_16x16x32_bf16(a, b, c, 0, 0, 0)

#if defined(__has_builtin)
#if __has_builtin(__builtin_amdgcn_mfma_f32_16x16x16bf16_1k)
#define HAVE_MFMA_K16 1
#endif
#if __has_builtin(__builtin_amdgcn_exp2f)
#define EXP2F __builtin_amdgcn_exp2f
#endif
#endif
#ifndef HAVE_MFMA_K16
#define HAVE_MFMA_K16 0
#endif
#ifndef EXP2F
#define EXP2F exp2f
#endif

#define NEG_BIG (-1e30f)
#define K2SCALE 0.18033688011112042f  /* 0.125 * log2(e) */

__device__ __forceinline__ short f2bf(float v) {
  return __builtin_bit_cast(short, __float2bfloat16(v));
}

// K=16 bf16 MFMA (A,B = 4 bf16/lane). Fallback: zero-padded K=32.
__device__ __forceinline__ f32x4 pv_mfma(bf16x4 va, bf16x4 pb, f32x4 c) {
#if HAVE_MFMA_K16
  return __builtin_amdgcn_mfma_f32_16x16x16bf16_1k(va, pb, c, 0, 0, 0);
#else
  const bf16x8 a = {va[0], va[1], va[2], va[3], 0, 0, 0, 0};
  const bf16x8 b = {pb[0], pb[1], pb[2], pb[3], 0, 0, 0, 0};
  return MFMA16(a, b, c);
#endif
}

// async global->LDS, 16B per lane. LDS dest = wave-uniform base + lane*16.
__device__ __forceinline__ void async_ld16(const bf16* g, bf16* l) {
  __builtin_amdgcn_global_load_lds(
      (const __attribute__((address_space(1))) unsigned int*)g,
      (__attribute__((address_space(3))) unsigned int*)l, 16, 0, 0);
}

template <typename T> __device__ __forceinline__ T cvt_out(float v);
template <> __device__ __forceinline__ float cvt_out<float>(float v) { return v; }
template <> __device__ __forceinline__ bf16 cvt_out<bf16>(float v) { return __float2bfloat16(v); }

// ---------------------------------------------------------------------------
// prep: one dispatch = x f32->bf16 convert + all four weight transposes.
// ---------------------------------------------------------------------------
__global__ void prep(const float* __restrict__ x,
                     const float* __restrict__ Wq, const float* __restrict__ Wk,
                     const float* __restrict__ Wv, const float* __restrict__ Wo,
                     bf16* __restrict__ xb, bf16* __restrict__ tq,
                     bf16* __restrict__ tk, bf16* __restrict__ tv,
                     bf16* __restrict__ to_) {
  __shared__ bf16 tile[32][33];
  const int bid = blockIdx.x;
  if (bid < 8192) {
    const int z = bid >> 11, tt = bid & 2047;
    const float* in = z == 0 ? Wq : z == 1 ? Wk : z == 2 ? Wv : Wo;
    bf16* out = z == 0 ? tq : z == 1 ? tk : z == 2 ? tv : to_;
    int R, Cc, c0, r0;
    if (z < 3) { R = 1024; Cc = 2048; c0 = (tt & 63) * 32; r0 = (tt >> 6) * 32; }
    else       { R = 2048; Cc = 1024; c0 = (tt & 31) * 32; r0 = (tt >> 5) * 32; }
    const int xx = threadIdx.x & 31;
    const int y = threadIdx.x >> 5;
#pragma unroll
    for (int yy = y; yy < 32; yy += 8)
      tile[yy][xx] = __float2bfloat16(in[(size_t)(r0 + yy) * Cc + c0 + xx]);
    __syncthreads();
#pragma unroll
    for (int yy = y; yy < 32; yy += 8)
      out[(size_t)(c0 + yy) * R + r0 + xx] = tile[xx][yy];
  } else {
    const int i = (bid - 8192) * 256 + threadIdx.x;  // < 1<<20 float4s
    const float4 v = ((const float4*)x)[i];
    bf16 o[4] = {__float2bfloat16(v.x), __float2bfloat16(v.y),
                 __float2bfloat16(v.z), __float2bfloat16(v.w)};
    *(uint64_t*)&xb[i * 4] = *(const uint64_t*)o;
  }
}

// ---------------------------------------------------------------------------
// Fused QKV projection: one dispatch, grid (512, 3).
// op=0: Q = xb @ WqT -> (b,h,n,d); op=1: K; op=2: V^T = wv @ xb^T -> (b,h,d,n)
//
// v2: BK=64 — two 16-MFMA K-steps per barrier pair (halves the per-barrier
// vmcnt(0)+lgkmcnt(0) drain count, the m97-structure's known ~20% stall).
// LDS 2x16KB = 32KB (occupancy unchanged; m132's BK=128 regression was the
// 64KB LDS cut, not the unroll). 64-elem rows are 128B -> would be a 16-way
// bank conflict on fragment reads, so staging uses flash's proven both-sides
// XOR involution: source chunk (t&7)^(row&7) lands at linear LDS (row, t&7);
// reads XOR the chunk index with (li&7). Lanes 0..7 of each 16-lane group
// hit 8 distinct banks; li/li+8 pair per bank = 2-way = free.
// ---------------------------------------------------------------------------
__global__ __launch_bounds__(256)
void gemm_qkv(const bf16* __restrict__ xb, const bf16* __restrict__ wq,
              const bf16* __restrict__ wk, const bf16* __restrict__ wv,
              bf16* __restrict__ qo, bf16* __restrict__ ko, bf16* __restrict__ vo) {
  __shared__ __align__(16) bf16 As[128 * 64];
  __shared__ __align__(16) bf16 Bs[128 * 64];
  const int op = blockIdx.y;
  const int bid = blockIdx.x;
  const bf16 *A, *B;
  int m0, n0;
  if (op < 2) { A = xb; B = op ? wk : wq; m0 = (bid >> 4) * 128; n0 = (bid & 15) * 128; }
  else        { A = wv; B = xb;           m0 = (bid & 15) * 128; n0 = (bid >> 4) * 128; }
  const int K = 1024;

  const int t = threadIdx.x;
  const int l = t & 63, w = t >> 6;
  const int q4 = l >> 4, li = l & 15;
  const int wr = (w >> 1) * 64, wc = (w & 1) * 64;

  f32x4 acc[4][4] = {};
  const int srow = t >> 3;             // row within 32-row staging round
  const int schu = t & 7;              // chunk (8 per 64-elem row)
  const int wavebase = (t & ~63) * 8;  // LDS elems, wave-uniform
  const bf16* gA = A + (size_t)m0 * K;
  const bf16* gB = B + (size_t)n0 * K;

  for (int k0 = 0; k0 < K; k0 += 64) {
#pragma unroll
    for (int p = 0; p < 4; ++p) {
      const int row = p * 32 + srow;
      const int cs = (schu ^ (row & 7)) * 8;
      const int lbase = p * 2048 + wavebase;
      async_ld16(gA + (size_t)row * K + k0 + cs, &As[lbase]);
      async_ld16(gB + (size_t)row * K + k0 + cs, &Bs[lbase]);
    }
    __syncthreads();
#pragma unroll
    for (int kk = 0; kk < 2; ++kk) {
      bf16x8 af[4], bfr[4];
#pragma unroll
      for (int i = 0; i < 4; ++i)
        af[i] = *(const bf16x8*)&As[(wr + i * 16 + li) * 64 +
                                    (((kk * 4 + q4) ^ (li & 7)) * 8)];
#pragma unroll
      for (int j = 0; j < 4; ++j)
        bfr[j] = *(const bf16x8*)&Bs[(wc + j * 16 + li) * 64 +
                                     (((kk * 4 + q4) ^ (li & 7)) * 8)];
#pragma unroll
      for (int i = 0; i < 4; ++i)
#pragma unroll
        for (int j = 0; j < 4; ++j)
          acc[i][j] = MFMA16(af[i], bfr[j], acc[i][j]);
    }
    __syncthreads();
  }

#pragma unroll
  for (int i = 0; i < 4; ++i)
#pragma unroll
    for (int j = 0; j < 4; ++j)
#pragma unroll
      for (int r = 0; r < 4; ++r) {
        const int gm = m0 + wr + i * 16 + q4 * 4 + r;
        const int gn = n0 + wc + j * 16 + li;
        const bf16 v = __float2bfloat16(acc[i][j][r]);
        if (op < 2) {
          const int b = gm >> 11, nn = gm & 2047;
          const int h = gn >> 7, d = gn & 127;
          (op ? ko : qo)[((size_t)(b * 16 + h) * 2048 + nn) * 128 + d] = v;
        } else {
          const int h = gm >> 7, d = gm & 127;
          const int b = gn >> 11, nn = gn & 2047;
          vo[((size_t)(b * 16 + h) * 128 + d) * 2048 + nn] = v;
        }
      }
}

// ---------------------------------------------------------------------------
// GEMM-BT (final projection): C[m][n] = sum_k A[m][k]*B[n][k], C row-major f32.
// NT=64 (round-5 proven config; the NT=128 experiment put 256 blocks at
// 1 block/CU and cost ~6us — no co-resident partner to hide barrier drains).
// ---------------------------------------------------------------------------
template <int NT, typename OT>
__global__ __launch_bounds__(256)
void gemm_bt(const bf16* __restrict__ A, const bf16* __restrict__ B,
             OT* __restrict__ C, int M, int N, int K) {
  __shared__ __align__(16) bf16 As[128 * 32];
  __shared__ __align__(16) bf16 Bs[NT * 32];
  constexpr int JN = NT / 32;
  const int t = threadIdx.x;
  const int l = t & 63, w = t >> 6;
  const int q4 = l >> 4, li = l & 15;
  const int m0 = blockIdx.y * 128;
  const int n0 = blockIdx.x * NT;
  const int wr = (w >> 1) * 64, wc = (w & 1) * (NT / 2);

  f32x4 acc[4][JN] = {};
  const int colst = (t & 3) * 8;
  const bf16* gA = A + (size_t)m0 * K;
  const bf16* gB = B + (size_t)n0 * K;

  for (int k0 = 0; k0 < K; k0 += 32) {
#pragma unroll
    for (int p = 0; p < 2; ++p) {
      const int row = p * 64 + (t >> 2);
      const int lbase = p * 2048 + (t & ~63) * 8;
      async_ld16(gA + (size_t)row * K + k0 + colst, &As[lbase]);
    }
#pragma unroll
    for (int p = 0; p < NT / 64; ++p) {
      const int row = p * 64 + (t >> 2);
      const int lbase = p * 2048 + (t & ~63) * 8;
      async_ld16(gB + (size_t)row * K + k0 + colst, &Bs[lbase]);
    }
    __syncthreads();
    bf16x8 af[4], bfr[JN];
#pragma unroll
    for (int i = 0; i < 4; ++i)
      af[i] = *(const bf16x8*)&As[(wr + i * 16 + li) * 32 + q4 * 8];
#pragma unroll
    for (int j = 0; j < JN; ++j)
      bfr[j] = *(const bf16x8*)&Bs[(wc + j * 16 + li) * 32 + q4 * 8];
#pragma unroll
    for (int i = 0; i < 4; ++i)
#pragma unroll
      for (int j = 0; j < JN; ++j)
        acc[i][j] = MFMA16(af[i], bfr[j], acc[i][j]);
    __syncthreads();
  }

#pragma unroll
  for (int i = 0; i < 4; ++i)
#pragma unroll
    for (int j = 0; j < JN; ++j)
#pragma unroll
      for (int r = 0; r < 4; ++r) {
        const int gm = m0 + wr + i * 16 + q4 * 4 + r;
        const int gn = n0 + wc + j * 16 + li;
        C[(size_t)gm * N + gn] = cvt_out<OT>(acc[i][j][r]);
      }
}

// ---------------------------------------------------------------------------
// Causal flash attention, S^T formulation.
//
// v10 (unchanged from round 9): v6 geometry + T5 s_setprio around the QK and
// PV MFMA clusters (measured −1.3us on flash). QT=64 (16q/wave), grid
// (32,32)=1024 blocks, K+V in LDS (64-key single-buffered, 16KB+16KB),
// launch_bounds(256,2), VGPR ~72, occupancy ~25%.
// TLP post-mortems (rounds 1/5/8): occupancy 13->26->31% gave 84->79.6->101us
// — the controlling quantity is useful-compute per fixed per-tile cost, and
// this geometry is its optimum among those tried.
// Keeps: source-XOR swizzle staging, fused exp2 softmax on raw scores,
// wave-uniform rescale skip, long-first dispatch, diagonal-only masking.
// ---------------------------------------------------------------------------
__global__ __launch_bounds__(256, 2)
void flash_attn(const bf16* __restrict__ qm, const bf16* __restrict__ km,
                const bf16* __restrict__ vtm, bf16* __restrict__ om) {
  __shared__ __align__(16) bf16 Ks[64 * 128];   // [key][d]
  __shared__ __align__(16) bf16 Vts[128 * 64];  // [d][key]

  const int t = threadIdx.x;
  const int l = t & 63, w = t >> 6;
  const int q4 = l >> 4, li = l & 15;
  const int bh = blockIdx.x;
  const int y = blockIdx.y;
  const int qt = (y < 16) ? 31 - y : y - 16;  // long blocks dispatch first
  const int qs = qt * 64;
  const size_t qkbase = (size_t)bh * 2048 * 128;
  const size_t vbase = (size_t)bh * 128 * 2048;
  const int b = bh >> 4, h = bh & 15;

  // Q fragments (B operand of S^T), 16 queries for this wave
  bf16x8 qf[4];
  {
    const bf16* Qb = qm + qkbase + (size_t)(qs + w * 16 + li) * 128;
#pragma unroll
    for (int f = 0; f < 4; ++f)
      qf[f] = *(const bf16x8*)(Qb + f * 32 + q4 * 8);
  }

  f32x4 O[8] = {};
  float mrun = NEG_BIG, lrun = 0.f;
  const int gmq = qs + w * 16 + li;  // this lane's query index

  // staging address components (per lane, constant across tiles)
  const int ksrow = t >> 4;            // K: row within 16-row group
  const int kchu = t & 15;             // K: chunk (16 per 128-elem row)
  const int vsrow = t >> 3;            // V: row within 32-row group
  const int vchu = t & 7;              // V: chunk (8 per 64-elem row)
  const int wavebase = (t & ~63) * 8;  // LDS elems, wave-uniform

  const int nt = qt + 1;  // number of 64-key tiles

  for (int j = 0; j < nt; ++j) {
    const int kb = j * 64;
    // stage K (64 keys x 128 d) and Vt (128 d x 64 keys) via async DMA,
    // source-swizzled: lane loads global chunk (chu)^(row&7), lands at
    // linear LDS position (row, chu).
#pragma unroll
    for (int p = 0; p < 4; ++p) {
      const int kr = p * 16 + ksrow;
      async_ld16(km + qkbase + (size_t)(kb + kr) * 128 + (size_t)((kchu ^ (kr & 7)) * 8),
                 &Ks[p * 2048 + wavebase]);
      const int vr = p * 32 + vsrow;
      async_ld16(vtm + vbase + (size_t)vr * 2048 + kb + (size_t)((vchu ^ (vr & 7)) * 8),
                 &Vts[p * 2048 + wavebase]);
    }
    __syncthreads();

    const bool msk = (j == qt);  // only the diagonal tile masks

    // S^T = K Q^T : S[jk] reg r = raw score(key = kb+jk*16+q4*4+r, query li)
    f32x4 S[4];
    __builtin_amdgcn_s_setprio(1);
#pragma unroll
    for (int jk = 0; jk < 4; ++jk) {
      const int krow = jk * 16 + li;
      bf16x8 kf[4];
#pragma unroll
      for (int f = 0; f < 4; ++f)
        kf[f] = *(const bf16x8*)&Ks[krow * 128 + (((f * 4 + q4) ^ (li & 7)) * 8)];
      f32x4 s = {0.f, 0.f, 0.f, 0.f};
#pragma unroll
      for (int f = 0; f < 4; ++f) s = MFMA16(kf[f], qf[f], s);
      S[jk] = s;
    }
    __builtin_amdgcn_s_setprio(0);

    if (msk) {
#pragma unroll
      for (int jk = 0; jk < 4; ++jk)
#pragma unroll
        for (int r = 0; r < 4; ++r)
          if ((kb + jk * 16 + q4 * 4 + r) > gmq) S[jk][r] = NEG_BIG;
    }

    // online softmax on raw scores
    float mx = NEG_BIG;
#pragma unroll
    for (int jk = 0; jk < 4; ++jk)
      mx = fmaxf(mx, fmaxf(fmaxf(S[jk][0], S[jk][1]), fmaxf(S[jk][2], S[jk][3])));
    mx = fmaxf(mx, __shfl_xor(mx, 16));
    mx = fmaxf(mx, __shfl_xor(mx, 32));
    const float mold = mrun;
    const float nm = fmaxf(mrun, mx);
    const bool nomove = (mx <= mold);
    mrun = nm;
    const float nmk = nm * K2SCALE;

    bf16x4 pb[4];
    float rs = 0.f;
#pragma unroll
    for (int jk = 0; jk < 4; ++jk) {
      float e[4];
#pragma unroll
      for (int r = 0; r < 4; ++r) {
        e[r] = EXP2F(__builtin_fmaf(S[jk][r], K2SCALE, -nmk));
        pb[jk][r] = f2bf(e[r]);
      }
      rs += (e[0] + e[1]) + (e[2] + e[3]);
    }
    rs += __shfl_xor(rs, 16);
    rs += __shfl_xor(rs, 32);

    if (__all(nomove)) {  // no lane's max moved: alpha == 1 everywhere
      lrun += rs;
    } else {
      const float alpha = EXP2F((mold - nm) * K2SCALE);
      lrun = lrun * alpha + rs;
#pragma unroll
      for (int dt = 0; dt < 8; ++dt) O[dt] *= alpha;
    }

    // O^T += V^T P^T : V^T from LDS (swizzled layout)
    __builtin_amdgcn_s_setprio(1);
#pragma unroll
    for (int dt = 0; dt < 8; ++dt)
#pragma unroll
      for (int kc = 0; kc < 4; ++kc) {
        const int gc = kc * 2 + (q4 >> 1);  // key-chunk within 64-key tile
        const bf16x4 va = *(const bf16x4*)&Vts[(dt * 16 + li) * 64 +
                                               ((gc ^ (li & 7)) * 8) +
                                               (q4 & 1) * 4];
        O[dt] = pv_mfma(va, pb[kc], O[dt]);
      }
    __builtin_amdgcn_s_setprio(0);
    __syncthreads();
  }

  // epilogue: normalize, write om[query][h*128+d], d = dt*16+q4*4+r
  {
    const float inv = 1.0f / lrun;
    const size_t orow = (size_t)(b * 2048 + qs + w * 16 + li) * 2048 + h * 128;
#pragma unroll
    for (int dt = 0; dt < 8; ++dt) {
      bf16x4 o4;
#pragma unroll
      for (int r = 0; r < 4; ++r) o4[r] = f2bf(O[dt][r] * inv);
      *(bf16x4*)&om[orow + dt * 16 + q4 * 4] = o4;
    }
  }
}

// ---------------------------------------------------------------------------
extern "C" void kernel_launch(void* const* d_in, const int* in_sizes, int n_in,
                              void* d_out, int out_size, void* d_ws, size_t ws_size,
                              hipStream_t stream) {
  const float* x = (const float*)d_in[0];
  const float* Wq = (const float*)d_in[1];
  const float* Wk = (const float*)d_in[2];
  const float* Wv = (const float*)d_in[3];
  const float* Wo = (const float*)d_in[4];
  float* out = (float*)d_out;

  // Workspace (bf16 elems), 36M = 72 MB:
  //   [0,4M) xb | [4M,6M) wTq | [6M,8M) wTk | [8M,10M) wTv | [10M,12M) woT
  //   [12M,20M) q_ws | [20M,28M) k_ws | [28M,36M) vt_ws
  //   at_ws = [2M,10M) (aliases xb-upper + wTq/k/v; dead before flash writes)
  bf16* ws = (bf16*)d_ws;
  const size_t MEG = 1u << 20;
  bf16* xb = ws;
  bf16* wTq = ws + 4 * MEG;
  bf16* wTk = ws + 6 * MEG;
  bf16* wTv = ws + 8 * MEG;
  bf16* woT = ws + 10 * MEG;
  bf16* at_ws = ws + 2 * MEG;
  bf16* q_ws = ws + 12 * MEG;
  bf16* k_ws = ws + 20 * MEG;
  bf16* vt_ws = ws + 28 * MEG;

  const dim3 blk(256);

  prep<<<dim3(12288), blk, 0, stream>>>(x, Wq, Wk, Wv, Wo, xb, wTq, wTk, wTv, woT);
  gemm_qkv<<<dim3(512, 3), blk, 0, stream>>>(xb, wTq, wTk, wTv, q_ws, k_ws, vt_ws);
  flash_attn<<<dim3(32, 32), blk, 0, stream>>>(q_ws, k_ws, vt_ws, at_ws);
  gemm_bt<64, float><<<dim3(16, 32), blk, 0, stream>>>(at_ws, woT, out, 4096, 1024, 2048);
}

// Round 11
// 254.766 us; speedup vs baseline: 1.1292x; 1.0450x over previous
//
#include <hip/hip_runtime.h>
#include <hip/hip_bf16.h>
#include <stdint.h>
#include <cmath>

using bf16 = __hip_bfloat16;
typedef __attribute__((ext_vector_type(8))) short bf16x8;
typedef __attribute__((ext_vector_type(4))) short bf16x4;
typedef __attribute__((ext_vector_type(4))) float f32x4;

#define MFMA16(a, b, c) __builtin_amdgcn_mfma_f32_16x16x32_bf16(a, b, c, 0, 0, 0)

#if defined(__has_builtin)
#if __has_builtin(__builtin_amdgcn_mfma_f32_16x16x16bf16_1k)
#define HAVE_MFMA_K16 1
#endif
#if __has_builtin(__builtin_amdgcn_exp2f)
#define EXP2F __builtin_amdgcn_exp2f
#endif
#endif
#ifndef HAVE_MFMA_K16
#define HAVE_MFMA_K16 0
#endif
#ifndef EXP2F
#define EXP2F exp2f
#endif

#define NEG_BIG (-1e30f)
#define K2SCALE 0.18033688011112042f  /* 0.125 * log2(e) */

__device__ __forceinline__ short f2bf(float v) {
  return __builtin_bit_cast(short, __float2bfloat16(v));
}

// K=16 bf16 MFMA (A,B = 4 bf16/lane). Fallback: zero-padded K=32.
__device__ __forceinline__ f32x4 pv_mfma(bf16x4 va, bf16x4 pb, f32x4 c) {
#if HAVE_MFMA_K16
  return __builtin_amdgcn_mfma_f32_16x16x16bf16_1k(va, pb, c, 0, 0, 0);
#else
  const bf16x8 a = {va[0], va[1], va[2], va[3], 0, 0, 0, 0};
  const bf16x8 b = {pb[0], pb[1], pb[2], pb[3], 0, 0, 0, 0};
  return MFMA16(a, b, c);
#endif
}

// async global->LDS, 16B per lane. LDS dest = wave-uniform base + lane*16.
__device__ __forceinline__ void async_ld16(const bf16* g, bf16* l) {
  __builtin_amdgcn_global_load_lds(
      (const __attribute__((address_space(1))) unsigned int*)g,
      (__attribute__((address_space(3))) unsigned int*)l, 16, 0, 0);
}

template <typename T> __device__ __forceinline__ T cvt_out(float v);
template <> __device__ __forceinline__ float cvt_out<float>(float v) { return v; }
template <> __device__ __forceinline__ bf16 cvt_out<bf16>(float v) { return __float2bfloat16(v); }

// ---------------------------------------------------------------------------
// prep: one dispatch = x f32->bf16 convert + all four weight transposes.
// v2: vectorized transpose I/O — lane owns a COLUMN PAIR: float2 loads (8B),
// 4B packed bf16x2 transposed stores (was scalar 2B stores — G13 applies to
// stores too). LDS pad 33 keeps read banks distinct (33*xx mod 32 = xx).
// ---------------------------------------------------------------------------
__global__ void prep(const float* __restrict__ x,
                     const float* __restrict__ Wq, const float* __restrict__ Wk,
                     const float* __restrict__ Wv, const float* __restrict__ Wo,
                     bf16* __restrict__ xb, bf16* __restrict__ tq,
                     bf16* __restrict__ tk, bf16* __restrict__ tv,
                     bf16* __restrict__ to_) {
  __shared__ bf16 tile[32][33];
  const int bid = blockIdx.x;
  if (bid < 8192) {
    const int z = bid >> 11, tt = bid & 2047;
    const float* in = z == 0 ? Wq : z == 1 ? Wk : z == 2 ? Wv : Wo;
    bf16* out = z == 0 ? tq : z == 1 ? tk : z == 2 ? tv : to_;
    int R, Cc, c0, r0;
    if (z < 3) { R = 1024; Cc = 2048; c0 = (tt & 63) * 32; r0 = (tt >> 6) * 32; }
    else       { R = 2048; Cc = 1024; c0 = (tt & 31) * 32; r0 = (tt >> 5) * 32; }
    const int xx = threadIdx.x & 15;   // column-pair id (covers cols 2xx,2xx+1)
    const int y = threadIdx.x >> 4;    // 0..15
#pragma unroll
    for (int yy = y; yy < 32; yy += 16) {
      const float2 v = *(const float2*)&in[(size_t)(r0 + yy) * Cc + c0 + 2 * xx];
      tile[yy][2 * xx] = __float2bfloat16(v.x);
      tile[yy][2 * xx + 1] = __float2bfloat16(v.y);
    }
    __syncthreads();
#pragma unroll
    for (int yy = y; yy < 32; yy += 16) {
      short o2[2] = {__builtin_bit_cast(short, tile[2 * xx][yy]),
                     __builtin_bit_cast(short, tile[2 * xx + 1][yy])};
      *(uint32_t*)&out[(size_t)(c0 + yy) * R + r0 + 2 * xx] = *(const uint32_t*)o2;
    }
  } else {
    const int i = (bid - 8192) * 256 + threadIdx.x;  // < 1<<20 float4s
    const float4 v = ((const float4*)x)[i];
    bf16 o[4] = {__float2bfloat16(v.x), __float2bfloat16(v.y),
                 __float2bfloat16(v.z), __float2bfloat16(v.w)};
    *(uint64_t*)&xb[i * 4] = *(const uint64_t*)o;
  }
}

// ---------------------------------------------------------------------------
// Fused QKV projection: one dispatch, grid (512, 3).
// op=0: Q = xb @ WqT -> (b,h,n,d); op=1: K; op=2: V^T = wv @ xb^T -> (b,h,d,n)
//
// BK=64 (proven round 10): two 16-MFMA K-steps per barrier pair; both-sides
// XOR involution keeps 64-elem (128B) rows conflict-free.
// ---------------------------------------------------------------------------
__global__ __launch_bounds__(256)
void gemm_qkv(const bf16* __restrict__ xb, const bf16* __restrict__ wq,
              const bf16* __restrict__ wk, const bf16* __restrict__ wv,
              bf16* __restrict__ qo, bf16* __restrict__ ko, bf16* __restrict__ vo) {
  __shared__ __align__(16) bf16 As[128 * 64];
  __shared__ __align__(16) bf16 Bs[128 * 64];
  const int op = blockIdx.y;
  const int bid = blockIdx.x;
  const bf16 *A, *B;
  int m0, n0;
  if (op < 2) { A = xb; B = op ? wk : wq; m0 = (bid >> 4) * 128; n0 = (bid & 15) * 128; }
  else        { A = wv; B = xb;           m0 = (bid & 15) * 128; n0 = (bid >> 4) * 128; }
  const int K = 1024;

  const int t = threadIdx.x;
  const int l = t & 63, w = t >> 6;
  const int q4 = l >> 4, li = l & 15;
  const int wr = (w >> 1) * 64, wc = (w & 1) * 64;

  f32x4 acc[4][4] = {};
  const int srow = t >> 3;             // row within 32-row staging round
  const int schu = t & 7;              // chunk (8 per 64-elem row)
  const int wavebase = (t & ~63) * 8;  // LDS elems, wave-uniform
  const bf16* gA = A + (size_t)m0 * K;
  const bf16* gB = B + (size_t)n0 * K;

  for (int k0 = 0; k0 < K; k0 += 64) {
#pragma unroll
    for (int p = 0; p < 4; ++p) {
      const int row = p * 32 + srow;
      const int cs = (schu ^ (row & 7)) * 8;
      const int lbase = p * 2048 + wavebase;
      async_ld16(gA + (size_t)row * K + k0 + cs, &As[lbase]);
      async_ld16(gB + (size_t)row * K + k0 + cs, &Bs[lbase]);
    }
    __syncthreads();
#pragma unroll
    for (int kk = 0; kk < 2; ++kk) {
      bf16x8 af[4], bfr[4];
#pragma unroll
      for (int i = 0; i < 4; ++i)
        af[i] = *(const bf16x8*)&As[(wr + i * 16 + li) * 64 +
                                    (((kk * 4 + q4) ^ (li & 7)) * 8)];
#pragma unroll
      for (int j = 0; j < 4; ++j)
        bfr[j] = *(const bf16x8*)&Bs[(wc + j * 16 + li) * 64 +
                                     (((kk * 4 + q4) ^ (li & 7)) * 8)];
#pragma unroll
      for (int i = 0; i < 4; ++i)
#pragma unroll
        for (int j = 0; j < 4; ++j)
          acc[i][j] = MFMA16(af[i], bfr[j], acc[i][j]);
    }
    __syncthreads();
  }

#pragma unroll
  for (int i = 0; i < 4; ++i)
#pragma unroll
    for (int j = 0; j < 4; ++j)
#pragma unroll
      for (int r = 0; r < 4; ++r) {
        const int gm = m0 + wr + i * 16 + q4 * 4 + r;
        const int gn = n0 + wc + j * 16 + li;
        const bf16 v = __float2bfloat16(acc[i][j][r]);
        if (op < 2) {
          const int b = gm >> 11, nn = gm & 2047;
          const int h = gn >> 7, d = gn & 127;
          (op ? ko : qo)[((size_t)(b * 16 + h) * 2048 + nn) * 128 + d] = v;
        } else {
          const int h = gm >> 7, d = gm & 127;
          const int b = gn >> 11, nn = gn & 2047;
          vo[((size_t)(b * 16 + h) * 128 + d) * 2048 + nn] = v;
        }
      }
}

// ---------------------------------------------------------------------------
// GEMM-BT (final projection): C[m][n] = sum_k A[m][k]*B[n][k], C row-major f32.
// NT=64 tile (proven), now with BK=64 like gemm_qkv: K=2048 -> 32 barrier
// pairs (was 64). Same both-sides XOR involution for the 128B rows.
// LDS = 16KB A + 8KB B = 24KB.
// ---------------------------------------------------------------------------
template <int NT, typename OT>
__global__ __launch_bounds__(256)
void gemm_bt(const bf16* __restrict__ A, const bf16* __restrict__ B,
             OT* __restrict__ C, int M, int N, int K) {
  __shared__ __align__(16) bf16 As[128 * 64];
  __shared__ __align__(16) bf16 Bs[NT * 64];
  constexpr int JN = NT / 32;
  const int t = threadIdx.x;
  const int l = t & 63, w = t >> 6;
  const int q4 = l >> 4, li = l & 15;
  const int m0 = blockIdx.y * 128;
  const int n0 = blockIdx.x * NT;
  const int wr = (w >> 1) * 64, wc = (w & 1) * (NT / 2);

  f32x4 acc[4][JN] = {};
  const int srow = t >> 3;             // row within 32-row staging round
  const int schu = t & 7;              // chunk (8 per 64-elem row)
  const int wavebase = (t & ~63) * 8;  // LDS elems, wave-uniform
  const bf16* gA = A + (size_t)m0 * K;
  const bf16* gB = B + (size_t)n0 * K;

  for (int k0 = 0; k0 < K; k0 += 64) {
#pragma unroll
    for (int p = 0; p < 4; ++p) {
      const int row = p * 32 + srow;
      const int cs = (schu ^ (row & 7)) * 8;
      async_ld16(gA + (size_t)row * K + k0 + cs, &As[p * 2048 + wavebase]);
    }
#pragma unroll
    for (int p = 0; p < NT / 32; ++p) {
      const int row = p * 32 + srow;
      const int cs = (schu ^ (row & 7)) * 8;
      async_ld16(gB + (size_t)row * K + k0 + cs, &Bs[p * 2048 + wavebase]);
    }
    __syncthreads();
#pragma unroll
    for (int kk = 0; kk < 2; ++kk) {
      bf16x8 af[4], bfr[JN];
#pragma unroll
      for (int i = 0; i < 4; ++i)
        af[i] = *(const bf16x8*)&As[(wr + i * 16 + li) * 64 +
                                    (((kk * 4 + q4) ^ (li & 7)) * 8)];
#pragma unroll
      for (int j = 0; j < JN; ++j)
        bfr[j] = *(const bf16x8*)&Bs[(wc + j * 16 + li) * 64 +
                                     (((kk * 4 + q4) ^ (li & 7)) * 8)];
#pragma unroll
      for (int i = 0; i < 4; ++i)
#pragma unroll
        for (int j = 0; j < JN; ++j)
          acc[i][j] = MFMA16(af[i], bfr[j], acc[i][j]);
    }
    __syncthreads();
  }

#pragma unroll
  for (int i = 0; i < 4; ++i)
#pragma unroll
    for (int j = 0; j < JN; ++j)
#pragma unroll
      for (int r = 0; r < 4; ++r) {
        const int gm = m0 + wr + i * 16 + q4 * 4 + r;
        const int gn = n0 + wc + j * 16 + li;
        C[(size_t)gm * N + gn] = cvt_out<OT>(acc[i][j][r]);
      }
}

// ---------------------------------------------------------------------------
// Causal flash attention, S^T formulation. (Unchanged from round 10.)
// v10: QT=64 (16q/wave), grid (32,32)=1024 blocks, K+V in LDS (64-key
// single-buffered, 16KB+16KB), launch_bounds(256,2), VGPR ~72, occupancy
// ~26%, + T5 s_setprio around QK/PV MFMA clusters (measured −1.3us).
// TLP post-mortems (rounds 1/5/8): occupancy 13->26->31% gave 84->79.6->101us
// — the controlling quantity is useful-compute per fixed per-tile cost; this
// geometry is its optimum among those tried.
// ---------------------------------------------------------------------------
__global__ __launch_bounds__(256, 2)
void flash_attn(const bf16* __restrict__ qm, const bf16* __restrict__ km,
                const bf16* __restrict__ vtm, bf16* __restrict__ om) {
  __shared__ __align__(16) bf16 Ks[64 * 128];   // [key][d]
  __shared__ __align__(16) bf16 Vts[128 * 64];  // [d][key]

  const int t = threadIdx.x;
  const int l = t & 63, w = t >> 6;
  const int q4 = l >> 4, li = l & 15;
  const int bh = blockIdx.x;
  const int y = blockIdx.y;
  const int qt = (y < 16) ? 31 - y : y - 16;  // long blocks dispatch first
  const int qs = qt * 64;
  const size_t qkbase = (size_t)bh * 2048 * 128;
  const size_t vbase = (size_t)bh * 128 * 2048;
  const int b = bh >> 4, h = bh & 15;

  // Q fragments (B operand of S^T), 16 queries for this wave
  bf16x8 qf[4];
  {
    const bf16* Qb = qm + qkbase + (size_t)(qs + w * 16 + li) * 128;
#pragma unroll
    for (int f = 0; f < 4; ++f)
      qf[f] = *(const bf16x8*)(Qb + f * 32 + q4 * 8);
  }

  f32x4 O[8] = {};
  float mrun = NEG_BIG, lrun = 0.f;
  const int gmq = qs + w * 16 + li;  // this lane's query index

  // staging address components (per lane, constant across tiles)
  const int ksrow = t >> 4;            // K: row within 16-row group
  const int kchu = t & 15;             // K: chunk (16 per 128-elem row)
  const int vsrow = t >> 3;            // V: row within 32-row group
  const int vchu = t & 7;              // V: chunk (8 per 64-elem row)
  const int wavebase = (t & ~63) * 8;  // LDS elems, wave-uniform

  const int nt = qt + 1;  // number of 64-key tiles

  for (int j = 0; j < nt; ++j) {
    const int kb = j * 64;
    // stage K (64 keys x 128 d) and Vt (128 d x 64 keys) via async DMA,
    // source-swizzled: lane loads global chunk (chu)^(row&7), lands at
    // linear LDS position (row, chu).
#pragma unroll
    for (int p = 0; p < 4; ++p) {
      const int kr = p * 16 + ksrow;
      async_ld16(km + qkbase + (size_t)(kb + kr) * 128 + (size_t)((kchu ^ (kr & 7)) * 8),
                 &Ks[p * 2048 + wavebase]);
      const int vr = p * 32 + vsrow;
      async_ld16(vtm + vbase + (size_t)vr * 2048 + kb + (size_t)((vchu ^ (vr & 7)) * 8),
                 &Vts[p * 2048 + wavebase]);
    }
    __syncthreads();

    const bool msk = (j == qt);  // only the diagonal tile masks

    // S^T = K Q^T : S[jk] reg r = raw score(key = kb+jk*16+q4*4+r, query li)
    f32x4 S[4];
    __builtin_amdgcn_s_setprio(1);
#pragma unroll
    for (int jk = 0; jk < 4; ++jk) {
      const int krow = jk * 16 + li;
      bf16x8 kf[4];
#pragma unroll
      for (int f = 0; f < 4; ++f)
        kf[f] = *(const bf16x8*)&Ks[krow * 128 + (((f * 4 + q4) ^ (li & 7)) * 8)];
      f32x4 s = {0.f, 0.f, 0.f, 0.f};
#pragma unroll
      for (int f = 0; f < 4; ++f) s = MFMA16(kf[f], qf[f], s);
      S[jk] = s;
    }
    __builtin_amdgcn_s_setprio(0);

    if (msk) {
#pragma unroll
      for (int jk = 0; jk < 4; ++jk)
#pragma unroll
        for (int r = 0; r < 4; ++r)
          if ((kb + jk * 16 + q4 * 4 + r) > gmq) S[jk][r] = NEG_BIG;
    }

    // online softmax on raw scores
    float mx = NEG_BIG;
#pragma unroll
    for (int jk = 0; jk < 4; ++jk)
      mx = fmaxf(mx, fmaxf(fmaxf(S[jk][0], S[jk][1]), fmaxf(S[jk][2], S[jk][3])));
    mx = fmaxf(mx, __shfl_xor(mx, 16));
    mx = fmaxf(mx, __shfl_xor(mx, 32));
    const float mold = mrun;
    const float nm = fmaxf(mrun, mx);
    const bool nomove = (mx <= mold);
    mrun = nm;
    const float nmk = nm * K2SCALE;

    bf16x4 pb[4];
    float rs = 0.f;
#pragma unroll
    for (int jk = 0; jk < 4; ++jk) {
      float e[4];
#pragma unroll
      for (int r = 0; r < 4; ++r) {
        e[r] = EXP2F(__builtin_fmaf(S[jk][r], K2SCALE, -nmk));
        pb[jk][r] = f2bf(e[r]);
      }
      rs += (e[0] + e[1]) + (e[2] + e[3]);
    }
    rs += __shfl_xor(rs, 16);
    rs += __shfl_xor(rs, 32);

    if (__all(nomove)) {  // no lane's max moved: alpha == 1 everywhere
      lrun += rs;
    } else {
      const float alpha = EXP2F((mold - nm) * K2SCALE);
      lrun = lrun * alpha + rs;
#pragma unroll
      for (int dt = 0; dt < 8; ++dt) O[dt] *= alpha;
    }

    // O^T += V^T P^T : V^T from LDS (swizzled layout)
    __builtin_amdgcn_s_setprio(1);
#pragma unroll
    for (int dt = 0; dt < 8; ++dt)
#pragma unroll
      for (int kc = 0; kc < 4; ++kc) {
        const int gc = kc * 2 + (q4 >> 1);  // key-chunk within 64-key tile
        const bf16x4 va = *(const bf16x4*)&Vts[(dt * 16 + li) * 64 +
                                               ((gc ^ (li & 7)) * 8) +
                                               (q4 & 1) * 4];
        O[dt] = pv_mfma(va, pb[kc], O[dt]);
      }
    __builtin_amdgcn_s_setprio(0);
    __syncthreads();
  }

  // epilogue: normalize, write om[query][h*128+d], d = dt*16+q4*4+r
  {
    const float inv = 1.0f / lrun;
    const size_t orow = (size_t)(b * 2048 + qs + w * 16 + li) * 2048 + h * 128;
#pragma unroll
    for (int dt = 0; dt < 8; ++dt) {
      bf16x4 o4;
#pragma unroll
      for (int r = 0; r < 4; ++r) o4[r] = f2bf(O[dt][r] * inv);
      *(bf16x4*)&om[orow + dt * 16 + q4 * 4] = o4;
    }
  }
}

// ---------------------------------------------------------------------------
extern "C" void kernel_launch(void* const* d_in, const int* in_sizes, int n_in,
                              void* d_out, int out_size, void* d_ws, size_t ws_size,
                              hipStream_t stream) {
  const float* x = (const float*)d_in[0];
  const float* Wq = (const float*)d_in[1];
  const float* Wk = (const float*)d_in[2];
  const float* Wv = (const float*)d_in[3];
  const float* Wo = (const float*)d_in[4];
  float* out = (float*)d_out;

  // Workspace (bf16 elems), 36M = 72 MB:
  //   [0,4M) xb | [4M,6M) wTq | [6M,8M) wTk | [8M,10M) wTv | [10M,12M) woT
  //   [12M,20M) q_ws | [20M,28M) k_ws | [28M,36M) vt_ws
  //   at_ws = [2M,10M) (aliases xb-upper + wTq/k/v; dead before flash writes)
  bf16* ws = (bf16*)d_ws;
  const size_t MEG = 1u << 20;
  bf16* xb = ws;
  bf16* wTq = ws + 4 * MEG;
  bf16* wTk = ws + 6 * MEG;
  bf16* wTv = ws + 8 * MEG;
  bf16* woT = ws + 10 * MEG;
  bf16* at_ws = ws + 2 * MEG;
  bf16* q_ws = ws + 12 * MEG;
  bf16* k_ws = ws + 20 * MEG;
  bf16* vt_ws = ws + 28 * MEG;

  const dim3 blk(256);

  prep<<<dim3(12288), blk, 0, stream>>>(x, Wq, Wk, Wv, Wo, xb, wTq, wTk, wTv, woT);
  gemm_qkv<<<dim3(512, 3), blk, 0, stream>>>(xb, wTq, wTk, wTv, q_ws, k_ws, vt_ws);
  flash_attn<<<dim3(32, 32), blk, 0, stream>>>(q_ws, k_ws, vt_ws, at_ws);
  gemm_bt<64, float><<<dim3(16, 32), blk, 0, stream>>>(at_ws, woT, out, 4096, 1024, 2048);
}

// Round 12
// 250.926 us; speedup vs baseline: 1.1465x; 1.0153x over previous
//
#include <hip/hip_runtime.h>
#include <hip/hip_bf16.h>
#include <stdint.h>
#include <cmath>

using bf16 = __hip_bfloat16;
typedef __attribute__((ext_vector_type(8))) short bf16x8;
typedef __attribute__((ext_vector_type(4))) short bf16x4;
typedef __attribute__((ext_vector_type(4))) float f32x4;

#define MFMA16(a, b, c) __builtin_amdgcn_mfma_f32_16x16x32_bf16(a, b, c, 0, 0, 0)

#if defined(__has_builtin)
#if __has_builtin(__builtin_amdgcn_mfma_f32_16x16x16bf16_1k)
#define HAVE_MFMA_K16 1
#endif
#if __has_builtin(__builtin_amdgcn_exp2f)
#define EXP2F __builtin_amdgcn_exp2f
#endif
#endif
#ifndef HAVE_MFMA_K16
#define HAVE_MFMA_K16 0
#endif
#ifndef EXP2F
#define EXP2F exp2f
#endif

#define NEG_BIG (-1e30f)
#define K2SCALE 0.18033688011112042f  /* 0.125 * log2(e) */

__device__ __forceinline__ short f2bf(float v) {
  return __builtin_bit_cast(short, __float2bfloat16(v));
}

// K=16 bf16 MFMA (A,B = 4 bf16/lane). Fallback: zero-padded K=32.
__device__ __forceinline__ f32x4 pv_mfma(bf16x4 va, bf16x4 pb, f32x4 c) {
#if HAVE_MFMA_K16
  return __builtin_amdgcn_mfma_f32_16x16x16bf16_1k(va, pb, c, 0, 0, 0);
#else
  const bf16x8 a = {va[0], va[1], va[2], va[3], 0, 0, 0, 0};
  const bf16x8 b = {pb[0], pb[1], pb[2], pb[3], 0, 0, 0, 0};
  return MFMA16(a, b, c);
#endif
}

// async global->LDS, 16B per lane. LDS dest = wave-uniform base + lane*16.
__device__ __forceinline__ void async_ld16(const bf16* g, bf16* l) {
  __builtin_amdgcn_global_load_lds(
      (const __attribute__((address_space(1))) unsigned int*)g,
      (__attribute__((address_space(3))) unsigned int*)l, 16, 0, 0);
}

template <typename T> __device__ __forceinline__ T cvt_out(float v);
template <> __device__ __forceinline__ float cvt_out<float>(float v) { return v; }
template <> __device__ __forceinline__ bf16 cvt_out<bf16>(float v) { return __float2bfloat16(v); }

// ---------------------------------------------------------------------------
// prep: one dispatch = x f32->bf16 convert + all four weight transposes.
// v2 (proven round 11): vectorized transpose I/O — float2 loads, 4B packed
// bf16x2 transposed stores. LDS pad 33 keeps read banks distinct.
// ---------------------------------------------------------------------------
__global__ void prep(const float* __restrict__ x,
                     const float* __restrict__ Wq, const float* __restrict__ Wk,
                     const float* __restrict__ Wv, const float* __restrict__ Wo,
                     bf16* __restrict__ xb, bf16* __restrict__ tq,
                     bf16* __restrict__ tk, bf16* __restrict__ tv,
                     bf16* __restrict__ to_) {
  __shared__ bf16 tile[32][33];
  const int bid = blockIdx.x;
  if (bid < 8192) {
    const int z = bid >> 11, tt = bid & 2047;
    const float* in = z == 0 ? Wq : z == 1 ? Wk : z == 2 ? Wv : Wo;
    bf16* out = z == 0 ? tq : z == 1 ? tk : z == 2 ? tv : to_;
    int R, Cc, c0, r0;
    if (z < 3) { R = 1024; Cc = 2048; c0 = (tt & 63) * 32; r0 = (tt >> 6) * 32; }
    else       { R = 2048; Cc = 1024; c0 = (tt & 31) * 32; r0 = (tt >> 5) * 32; }
    const int xx = threadIdx.x & 15;   // column-pair id (covers cols 2xx,2xx+1)
    const int y = threadIdx.x >> 4;    // 0..15
#pragma unroll
    for (int yy = y; yy < 32; yy += 16) {
      const float2 v = *(const float2*)&in[(size_t)(r0 + yy) * Cc + c0 + 2 * xx];
      tile[yy][2 * xx] = __float2bfloat16(v.x);
      tile[yy][2 * xx + 1] = __float2bfloat16(v.y);
    }
    __syncthreads();
#pragma unroll
    for (int yy = y; yy < 32; yy += 16) {
      short o2[2] = {__builtin_bit_cast(short, tile[2 * xx][yy]),
                     __builtin_bit_cast(short, tile[2 * xx + 1][yy])};
      *(uint32_t*)&out[(size_t)(c0 + yy) * R + r0 + 2 * xx] = *(const uint32_t*)o2;
    }
  } else {
    const int i = (bid - 8192) * 256 + threadIdx.x;  // < 1<<20 float4s
    const float4 v = ((const float4*)x)[i];
    bf16 o[4] = {__float2bfloat16(v.x), __float2bfloat16(v.y),
                 __float2bfloat16(v.z), __float2bfloat16(v.w)};
    *(uint64_t*)&xb[i * 4] = *(const uint64_t*)o;
  }
}

// ---------------------------------------------------------------------------
// Fused QKV projection: one dispatch, grid (512, 3).
// op=0: Q = xb @ WqT -> (b,h,n,d); op=1: K; op=2: V^T = wv @ xb^T -> (b,h,d,n)
//
// BK=64 (proven round 10): two 16-MFMA K-steps per barrier pair; both-sides
// XOR involution keeps 64-elem (128B) rows conflict-free.
// ---------------------------------------------------------------------------
__global__ __launch_bounds__(256)
void gemm_qkv(const bf16* __restrict__ xb, const bf16* __restrict__ wq,
              const bf16* __restrict__ wk, const bf16* __restrict__ wv,
              bf16* __restrict__ qo, bf16* __restrict__ ko, bf16* __restrict__ vo) {
  __shared__ __align__(16) bf16 As[128 * 64];
  __shared__ __align__(16) bf16 Bs[128 * 64];
  const int op = blockIdx.y;
  const int bid = blockIdx.x;
  const bf16 *A, *B;
  int m0, n0;
  if (op < 2) { A = xb; B = op ? wk : wq; m0 = (bid >> 4) * 128; n0 = (bid & 15) * 128; }
  else        { A = wv; B = xb;           m0 = (bid & 15) * 128; n0 = (bid >> 4) * 128; }
  const int K = 1024;

  const int t = threadIdx.x;
  const int l = t & 63, w = t >> 6;
  const int q4 = l >> 4, li = l & 15;
  const int wr = (w >> 1) * 64, wc = (w & 1) * 64;

  f32x4 acc[4][4] = {};
  const int srow = t >> 3;             // row within 32-row staging round
  const int schu = t & 7;              // chunk (8 per 64-elem row)
  const int wavebase = (t & ~63) * 8;  // LDS elems, wave-uniform
  const bf16* gA = A + (size_t)m0 * K;
  const bf16* gB = B + (size_t)n0 * K;

  for (int k0 = 0; k0 < K; k0 += 64) {
#pragma unroll
    for (int p = 0; p < 4; ++p) {
      const int row = p * 32 + srow;
      const int cs = (schu ^ (row & 7)) * 8;
      const int lbase = p * 2048 + wavebase;
      async_ld16(gA + (size_t)row * K + k0 + cs, &As[lbase]);
      async_ld16(gB + (size_t)row * K + k0 + cs, &Bs[lbase]);
    }
    __syncthreads();
#pragma unroll
    for (int kk = 0; kk < 2; ++kk) {
      bf16x8 af[4], bfr[4];
#pragma unroll
      for (int i = 0; i < 4; ++i)
        af[i] = *(const bf16x8*)&As[(wr + i * 16 + li) * 64 +
                                    (((kk * 4 + q4) ^ (li & 7)) * 8)];
#pragma unroll
      for (int j = 0; j < 4; ++j)
        bfr[j] = *(const bf16x8*)&Bs[(wc + j * 16 + li) * 64 +
                                     (((kk * 4 + q4) ^ (li & 7)) * 8)];
#pragma unroll
      for (int i = 0; i < 4; ++i)
#pragma unroll
        for (int j = 0; j < 4; ++j)
          acc[i][j] = MFMA16(af[i], bfr[j], acc[i][j]);
    }
    __syncthreads();
  }

#pragma unroll
  for (int i = 0; i < 4; ++i)
#pragma unroll
    for (int j = 0; j < 4; ++j)
#pragma unroll
      for (int r = 0; r < 4; ++r) {
        const int gm = m0 + wr + i * 16 + q4 * 4 + r;
        const int gn = n0 + wc + j * 16 + li;
        const bf16 v = __float2bfloat16(acc[i][j][r]);
        if (op < 2) {
          const int b = gm >> 11, nn = gm & 2047;
          const int h = gn >> 7, d = gn & 127;
          (op ? ko : qo)[((size_t)(b * 16 + h) * 2048 + nn) * 128 + d] = v;
        } else {
          const int h = gm >> 7, d = gm & 127;
          const int b = gn >> 11, nn = gn & 2047;
          vo[((size_t)(b * 16 + h) * 128 + d) * 2048 + nn] = v;
        }
      }
}

// ---------------------------------------------------------------------------
// GEMM-BT (final projection): C[m][n] = sum_k A[m][k]*B[n][k], C row-major f32.
// NT=64 tile, BK=64 + XOR involution (proven round 11): K=2048 -> 32 barrier
// pairs. LDS = 16KB A + 8KB B = 24KB.
// ---------------------------------------------------------------------------
template <int NT, typename OT>
__global__ __launch_bounds__(256)
void gemm_bt(const bf16* __restrict__ A, const bf16* __restrict__ B,
             OT* __restrict__ C, int M, int N, int K) {
  __shared__ __align__(16) bf16 As[128 * 64];
  __shared__ __align__(16) bf16 Bs[NT * 64];
  constexpr int JN = NT / 32;
  const int t = threadIdx.x;
  const int l = t & 63, w = t >> 6;
  const int q4 = l >> 4, li = l & 15;
  const int m0 = blockIdx.y * 128;
  const int n0 = blockIdx.x * NT;
  const int wr = (w >> 1) * 64, wc = (w & 1) * (NT / 2);

  f32x4 acc[4][JN] = {};
  const int srow = t >> 3;             // row within 32-row staging round
  const int schu = t & 7;              // chunk (8 per 64-elem row)
  const int wavebase = (t & ~63) * 8;  // LDS elems, wave-uniform
  const bf16* gA = A + (size_t)m0 * K;
  const bf16* gB = B + (size_t)n0 * K;

  for (int k0 = 0; k0 < K; k0 += 64) {
#pragma unroll
    for (int p = 0; p < 4; ++p) {
      const int row = p * 32 + srow;
      const int cs = (schu ^ (row & 7)) * 8;
      async_ld16(gA + (size_t)row * K + k0 + cs, &As[p * 2048 + wavebase]);
    }
#pragma unroll
    for (int p = 0; p < NT / 32; ++p) {
      const int row = p * 32 + srow;
      const int cs = (schu ^ (row & 7)) * 8;
      async_ld16(gB + (size_t)row * K + k0 + cs, &Bs[p * 2048 + wavebase]);
    }
    __syncthreads();
#pragma unroll
    for (int kk = 0; kk < 2; ++kk) {
      bf16x8 af[4], bfr[JN];
#pragma unroll
      for (int i = 0; i < 4; ++i)
        af[i] = *(const bf16x8*)&As[(wr + i * 16 + li) * 64 +
                                    (((kk * 4 + q4) ^ (li & 7)) * 8)];
#pragma unroll
      for (int j = 0; j < JN; ++j)
        bfr[j] = *(const bf16x8*)&Bs[(wc + j * 16 + li) * 64 +
                                     (((kk * 4 + q4) ^ (li & 7)) * 8)];
#pragma unroll
      for (int i = 0; i < 4; ++i)
#pragma unroll
        for (int j = 0; j < JN; ++j)
          acc[i][j] = MFMA16(af[i], bfr[j], acc[i][j]);
    }
    __syncthreads();
  }

#pragma unroll
  for (int i = 0; i < 4; ++i)
#pragma unroll
    for (int j = 0; j < JN; ++j)
#pragma unroll
      for (int r = 0; r < 4; ++r) {
        const int gm = m0 + wr + i * 16 + q4 * 4 + r;
        const int gn = n0 + wc + j * 16 + li;
        C[(size_t)gm * N + gn] = cvt_out<OT>(acc[i][j][r]);
      }
}

// ---------------------------------------------------------------------------
// Causal flash attention, S^T formulation.
//
// v11 = v10 + T13 defer-max (RESCALE_THRESHOLD=8, HK's value; m214v23 +5%,
// m239 correctness for online-max): keep the old running max unless some
// lane's tile-max exceeds it by >8 exp2-argument units. P values are then
// bounded by 2^8=256 (bf16-safe; lrun <= ~5e5 in f32). The old strict
// nomove check was the THR=0 special case — nearly every tile paid the
// divergent 32-multiply O-rescale. Decision is made wave-wide BEFORE
// computing e (single exp base), which also simplifies the dataflow.
// Structure otherwise v10: QT=64 (16q/wave), grid (32,32)=1024 blocks, K+V
// in LDS (64-key single-buffered, 16KB+16KB), bounds(256,2), setprio around
// QK/PV MFMA clusters, source-XOR staging, fused exp2, long-first dispatch.
// LDS access patterns are at the per-bank floor (4 addr/bank for PV b64,
// analytic); TLP exhausted (occupancy 13/26/31% -> 84/79.6/101us).
// ---------------------------------------------------------------------------
__global__ __launch_bounds__(256, 2)
void flash_attn(const bf16* __restrict__ qm, const bf16* __restrict__ km,
                const bf16* __restrict__ vtm, bf16* __restrict__ om) {
  __shared__ __align__(16) bf16 Ks[64 * 128];   // [key][d]
  __shared__ __align__(16) bf16 Vts[128 * 64];  // [d][key]

  const int t = threadIdx.x;
  const int l = t & 63, w = t >> 6;
  const int q4 = l >> 4, li = l & 15;
  const int bh = blockIdx.x;
  const int y = blockIdx.y;
  const int qt = (y < 16) ? 31 - y : y - 16;  // long blocks dispatch first
  const int qs = qt * 64;
  const size_t qkbase = (size_t)bh * 2048 * 128;
  const size_t vbase = (size_t)bh * 128 * 2048;
  const int b = bh >> 4, h = bh & 15;

  // Q fragments (B operand of S^T), 16 queries for this wave
  bf16x8 qf[4];
  {
    const bf16* Qb = qm + qkbase + (size_t)(qs + w * 16 + li) * 128;
#pragma unroll
    for (int f = 0; f < 4; ++f)
      qf[f] = *(const bf16x8*)(Qb + f * 32 + q4 * 8);
  }

  f32x4 O[8] = {};
  float mrun = NEG_BIG, lrun = 0.f;
  const int gmq = qs + w * 16 + li;  // this lane's query index

  // staging address components (per lane, constant across tiles)
  const int ksrow = t >> 4;            // K: row within 16-row group
  const int kchu = t & 15;             // K: chunk (16 per 128-elem row)
  const int vsrow = t >> 3;            // V: row within 32-row group
  const int vchu = t & 7;              // V: chunk (8 per 64-elem row)
  const int wavebase = (t & ~63) * 8;  // LDS elems, wave-uniform

  const int nt = qt + 1;  // number of 64-key tiles

  for (int j = 0; j < nt; ++j) {
    const int kb = j * 64;
    // stage K (64 keys x 128 d) and Vt (128 d x 64 keys) via async DMA,
    // source-swizzled: lane loads global chunk (chu)^(row&7), lands at
    // linear LDS position (row, chu).
#pragma unroll
    for (int p = 0; p < 4; ++p) {
      const int kr = p * 16 + ksrow;
      async_ld16(km + qkbase + (size_t)(kb + kr) * 128 + (size_t)((kchu ^ (kr & 7)) * 8),
                 &Ks[p * 2048 + wavebase]);
      const int vr = p * 32 + vsrow;
      async_ld16(vtm + vbase + (size_t)vr * 2048 + kb + (size_t)((vchu ^ (vr & 7)) * 8),
                 &Vts[p * 2048 + wavebase]);
    }
    __syncthreads();

    const bool msk = (j == qt);  // only the diagonal tile masks

    // S^T = K Q^T : S[jk] reg r = raw score(key = kb+jk*16+q4*4+r, query li)
    f32x4 S[4];
    __builtin_amdgcn_s_setprio(1);
#pragma unroll
    for (int jk = 0; jk < 4; ++jk) {
      const int krow = jk * 16 + li;
      bf16x8 kf[4];
#pragma unroll
      for (int f = 0; f < 4; ++f)
        kf[f] = *(const bf16x8*)&Ks[krow * 128 + (((f * 4 + q4) ^ (li & 7)) * 8)];
      f32x4 s = {0.f, 0.f, 0.f, 0.f};
#pragma unroll
      for (int f = 0; f < 4; ++f) s = MFMA16(kf[f], qf[f], s);
      S[jk] = s;
    }
    __builtin_amdgcn_s_setprio(0);

    if (msk) {
#pragma unroll
      for (int jk = 0; jk < 4; ++jk)
#pragma unroll
        for (int r = 0; r < 4; ++r)
          if ((kb + jk * 16 + q4 * 4 + r) > gmq) S[jk][r] = NEG_BIG;
    }

    // tile max (per query li, uniform across the 4 q4 lanes)
    float mx = NEG_BIG;
#pragma unroll
    for (int jk = 0; jk < 4; ++jk)
      mx = fmaxf(mx, fmaxf(fmaxf(S[jk][0], S[jk][1]), fmaxf(S[jk][2], S[jk][3])));
    mx = fmaxf(mx, __shfl_xor(mx, 16));
    mx = fmaxf(mx, __shfl_xor(mx, 32));

    // T13 defer-max: keep old running max unless growth > 8 exp2-arg units
    // (then P <= 2^8 = 256; bf16/f32-safe). Wave-uniform decision BEFORE e.
    const float mold = mrun;
    const bool keep = __all((mx - mrun) * K2SCALE <= 8.0f);
    if (!keep) mrun = fmaxf(mrun, mx);
    const float nmk = mrun * K2SCALE;

    bf16x4 pb[4];
    float rs = 0.f;
#pragma unroll
    for (int jk = 0; jk < 4; ++jk) {
      float e[4];
#pragma unroll
      for (int r = 0; r < 4; ++r) {
        e[r] = EXP2F(__builtin_fmaf(S[jk][r], K2SCALE, -nmk));
        pb[jk][r] = f2bf(e[r]);
      }
      rs += (e[0] + e[1]) + (e[2] + e[3]);
    }
    rs += __shfl_xor(rs, 16);
    rs += __shfl_xor(rs, 32);

    if (keep) {  // running max unchanged: alpha == 1 everywhere
      lrun += rs;
    } else {
      const float alpha = EXP2F((mold - mrun) * K2SCALE);
      lrun = lrun * alpha + rs;
#pragma unroll
      for (int dt = 0; dt < 8; ++dt) O[dt] *= alpha;
    }

    // O^T += V^T P^T : V^T from LDS (swizzled layout)
    __builtin_amdgcn_s_setprio(1);
#pragma unroll
    for (int dt = 0; dt < 8; ++dt)
#pragma unroll
      for (int kc = 0; kc < 4; ++kc) {
        const int gc = kc * 2 + (q4 >> 1);  // key-chunk within 64-key tile
        const bf16x4 va = *(const bf16x4*)&Vts[(dt * 16 + li) * 64 +
                                               ((gc ^ (li & 7)) * 8) +
                                               (q4 & 1) * 4];
        O[dt] = pv_mfma(va, pb[kc], O[dt]);
      }
    __builtin_amdgcn_s_setprio(0);
    __syncthreads();
  }

  // epilogue: normalize, write om[query][h*128+d], d = dt*16+q4*4+r
  {
    const float inv = 1.0f / lrun;
    const size_t orow = (size_t)(b * 2048 + qs + w * 16 + li) * 2048 + h * 128;
#pragma unroll
    for (int dt = 0; dt < 8; ++dt) {
      bf16x4 o4;
#pragma unroll
      for (int r = 0; r < 4; ++r) o4[r] = f2bf(O[dt][r] * inv);
      *(bf16x4*)&om[orow + dt * 16 + q4 * 4] = o4;
    }
  }
}

// ---------------------------------------------------------------------------
extern "C" void kernel_launch(void* const* d_in, const int* in_sizes, int n_in,
                              void* d_out, int out_size, void* d_ws, size_t ws_size,
                              hipStream_t stream) {
  const float* x = (const float*)d_in[0];
  const float* Wq = (const float*)d_in[1];
  const float* Wk = (const float*)d_in[2];
  const float* Wv = (const float*)d_in[3];
  const float* Wo = (const float*)d_in[4];
  float* out = (float*)d_out;

  // Workspace (bf16 elems), 36M = 72 MB:
  //   [0,4M) xb | [4M,6M) wTq | [6M,8M) wTk | [8M,10M) wTv | [10M,12M) woT
  //   [12M,20M) q_ws | [20M,28M) k_ws | [28M,36M) vt_ws
  //   at_ws = [2M,10M) (aliases xb-upper + wTq/k/v; dead before flash writes)
  bf16* ws = (bf16*)d_ws;
  const size_t MEG = 1u << 20;
  bf16* xb = ws;
  bf16* wTq = ws + 4 * MEG;
  bf16* wTk = ws + 6 * MEG;
  bf16* wTv = ws + 8 * MEG;
  bf16* woT = ws + 10 * MEG;
  bf16* at_ws = ws + 2 * MEG;
  bf16* q_ws = ws + 12 * MEG;
  bf16* k_ws = ws + 20 * MEG;
  bf16* vt_ws = ws + 28 * MEG;

  const dim3 blk(256);

  prep<<<dim3(12288), blk, 0, stream>>>(x, Wq, Wk, Wv, Wo, xb, wTq, wTk, wTv, woT);
  gemm_qkv<<<dim3(512, 3), blk, 0, stream>>>(xb, wTq, wTk, wTv, q_ws, k_ws, vt_ws);
  flash_attn<<<dim3(32, 32), blk, 0, stream>>>(q_ws, k_ws, vt_ws, at_ws);
  gemm_bt<64, float><<<dim3(16, 32), blk, 0, stream>>>(at_ws, woT, out, 4096, 1024, 2048);
}

// Round 13
// 248.643 us; speedup vs baseline: 1.1570x; 1.0092x over previous
//
#include <hip/hip_runtime.h>
#include <hip/hip_bf16.h>
#include <stdint.h>
#include <cmath>

using bf16 = __hip_bfloat16;
typedef __attribute__((ext_vector_type(8))) short bf16x8;
typedef __attribute__((ext_vector_type(4))) short bf16x4;
typedef __attribute__((ext_vector_type(4))) float f32x4;

#define MFMA16(a, b, c) __builtin_amdgcn_mfma_f32_16x16x32_bf16(a, b, c, 0, 0, 0)

#if defined(__has_builtin)
#if __has_builtin(__builtin_amdgcn_mfma_f32_16x16x16bf16_1k)
#define HAVE_MFMA_K16 1
#endif
#if __has_builtin(__builtin_amdgcn_exp2f)
#define EXP2F __builtin_amdgcn_exp2f
#endif
#endif
#ifndef HAVE_MFMA_K16
#define HAVE_MFMA_K16 0
#endif
#ifndef EXP2F
#define EXP2F exp2f
#endif

#define NEG_BIG (-1e30f)
#define K2SCALE 0.18033688011112042f  /* 0.125 * log2(e) */

__device__ __forceinline__ short f2bf(float v) {
  return __builtin_bit_cast(short, __float2bfloat16(v));
}

// K=16 bf16 MFMA (A,B = 4 bf16/lane). Fallback: zero-padded K=32.
__device__ __forceinline__ f32x4 pv_mfma(bf16x4 va, bf16x4 pb, f32x4 c) {
#if HAVE_MFMA_K16
  return __builtin_amdgcn_mfma_f32_16x16x16bf16_1k(va, pb, c, 0, 0, 0);
#else
  const bf16x8 a = {va[0], va[1], va[2], va[3], 0, 0, 0, 0};
  const bf16x8 b = {pb[0], pb[1], pb[2], pb[3], 0, 0, 0, 0};
  return MFMA16(a, b, c);
#endif
}

// async global->LDS, 16B per lane. LDS dest = wave-uniform base + lane*16.
__device__ __forceinline__ void async_ld16(const bf16* g, bf16* l) {
  __builtin_amdgcn_global_load_lds(
      (const __attribute__((address_space(1))) unsigned int*)g,
      (__attribute__((address_space(3))) unsigned int*)l, 16, 0, 0);
}

template <typename T> __device__ __forceinline__ T cvt_out(float v);
template <> __device__ __forceinline__ float cvt_out<float>(float v) { return v; }
template <> __device__ __forceinline__ bf16 cvt_out<bf16>(float v) { return __float2bfloat16(v); }

// ---------------------------------------------------------------------------
// prep: one dispatch = x f32->bf16 convert + all four weight transposes.
// v2 (proven round 11): vectorized transpose I/O — float2 loads, 4B packed
// bf16x2 transposed stores. LDS pad 33 keeps read banks distinct.
// ---------------------------------------------------------------------------
__global__ void prep(const float* __restrict__ x,
                     const float* __restrict__ Wq, const float* __restrict__ Wk,
                     const float* __restrict__ Wv, const float* __restrict__ Wo,
                     bf16* __restrict__ xb, bf16* __restrict__ tq,
                     bf16* __restrict__ tk, bf16* __restrict__ tv,
                     bf16* __restrict__ to_) {
  __shared__ bf16 tile[32][33];
  const int bid = blockIdx.x;
  if (bid < 8192) {
    const int z = bid >> 11, tt = bid & 2047;
    const float* in = z == 0 ? Wq : z == 1 ? Wk : z == 2 ? Wv : Wo;
    bf16* out = z == 0 ? tq : z == 1 ? tk : z == 2 ? tv : to_;
    int R, Cc, c0, r0;
    if (z < 3) { R = 1024; Cc = 2048; c0 = (tt & 63) * 32; r0 = (tt >> 6) * 32; }
    else       { R = 2048; Cc = 1024; c0 = (tt & 31) * 32; r0 = (tt >> 5) * 32; }
    const int xx = threadIdx.x & 15;   // column-pair id (covers cols 2xx,2xx+1)
    const int y = threadIdx.x >> 4;    // 0..15
#pragma unroll
    for (int yy = y; yy < 32; yy += 16) {
      const float2 v = *(const float2*)&in[(size_t)(r0 + yy) * Cc + c0 + 2 * xx];
      tile[yy][2 * xx] = __float2bfloat16(v.x);
      tile[yy][2 * xx + 1] = __float2bfloat16(v.y);
    }
    __syncthreads();
#pragma unroll
    for (int yy = y; yy < 32; yy += 16) {
      short o2[2] = {__builtin_bit_cast(short, tile[2 * xx][yy]),
                     __builtin_bit_cast(short, tile[2 * xx + 1][yy])};
      *(uint32_t*)&out[(size_t)(c0 + yy) * R + r0 + 2 * xx] = *(const uint32_t*)o2;
    }
  } else {
    const int i = (bid - 8192) * 256 + threadIdx.x;  // < 1<<20 float4s
    const float4 v = ((const float4*)x)[i];
    bf16 o[4] = {__float2bfloat16(v.x), __float2bfloat16(v.y),
                 __float2bfloat16(v.z), __float2bfloat16(v.w)};
    *(uint64_t*)&xb[i * 4] = *(const uint64_t*)o;
  }
}

// ---------------------------------------------------------------------------
// Fused QKV projection: one dispatch, grid (512, 3).
// op=0: Q = xb @ WqT -> (b,h,n,d); op=1: K; op=2: V^T = wv @ xb^T -> (b,h,d,n)
//
// BK=64 (proven round 10): two 16-MFMA K-steps per barrier pair; both-sides
// XOR involution keeps 64-elem (128B) rows conflict-free.
// v3: T1 XCD-aware block swizzle — default round-robin gives each XCD's
// resident blocks all 32 m-panels + 16 n-panels ~= 12MB >> 4MB private L2;
// remap (bid&7)*64 + bid>>3 (bijective, 512%8==0) makes each XCD's blocks a
// contiguous 64-tile chunk: 4 m-panels + all n-panels ~= 5MB, near-L2-fit.
// ---------------------------------------------------------------------------
__global__ __launch_bounds__(256)
void gemm_qkv(const bf16* __restrict__ xb, const bf16* __restrict__ wq,
              const bf16* __restrict__ wk, const bf16* __restrict__ wv,
              bf16* __restrict__ qo, bf16* __restrict__ ko, bf16* __restrict__ vo) {
  __shared__ __align__(16) bf16 As[128 * 64];
  __shared__ __align__(16) bf16 Bs[128 * 64];
  const int op = blockIdx.y;
  const int bid0 = blockIdx.x;
  const int bid = ((bid0 & 7) << 6) | (bid0 >> 3);  // XCD-contiguous remap
  const bf16 *A, *B;
  int m0, n0;
  if (op < 2) { A = xb; B = op ? wk : wq; m0 = (bid >> 4) * 128; n0 = (bid & 15) * 128; }
  else        { A = wv; B = xb;           m0 = (bid & 15) * 128; n0 = (bid >> 4) * 128; }
  const int K = 1024;

  const int t = threadIdx.x;
  const int l = t & 63, w = t >> 6;
  const int q4 = l >> 4, li = l & 15;
  const int wr = (w >> 1) * 64, wc = (w & 1) * 64;

  f32x4 acc[4][4] = {};
  const int srow = t >> 3;             // row within 32-row staging round
  const int schu = t & 7;              // chunk (8 per 64-elem row)
  const int wavebase = (t & ~63) * 8;  // LDS elems, wave-uniform
  const bf16* gA = A + (size_t)m0 * K;
  const bf16* gB = B + (size_t)n0 * K;

  for (int k0 = 0; k0 < K; k0 += 64) {
#pragma unroll
    for (int p = 0; p < 4; ++p) {
      const int row = p * 32 + srow;
      const int cs = (schu ^ (row & 7)) * 8;
      const int lbase = p * 2048 + wavebase;
      async_ld16(gA + (size_t)row * K + k0 + cs, &As[lbase]);
      async_ld16(gB + (size_t)row * K + k0 + cs, &Bs[lbase]);
    }
    __syncthreads();
#pragma unroll
    for (int kk = 0; kk < 2; ++kk) {
      bf16x8 af[4], bfr[4];
#pragma unroll
      for (int i = 0; i < 4; ++i)
        af[i] = *(const bf16x8*)&As[(wr + i * 16 + li) * 64 +
                                    (((kk * 4 + q4) ^ (li & 7)) * 8)];
#pragma unroll
      for (int j = 0; j < 4; ++j)
        bfr[j] = *(const bf16x8*)&Bs[(wc + j * 16 + li) * 64 +
                                     (((kk * 4 + q4) ^ (li & 7)) * 8)];
#pragma unroll
      for (int i = 0; i < 4; ++i)
#pragma unroll
        for (int j = 0; j < 4; ++j)
          acc[i][j] = MFMA16(af[i], bfr[j], acc[i][j]);
    }
    __syncthreads();
  }

#pragma unroll
  for (int i = 0; i < 4; ++i)
#pragma unroll
    for (int j = 0; j < 4; ++j)
#pragma unroll
      for (int r = 0; r < 4; ++r) {
        const int gm = m0 + wr + i * 16 + q4 * 4 + r;
        const int gn = n0 + wc + j * 16 + li;
        const bf16 v = __float2bfloat16(acc[i][j][r]);
        if (op < 2) {
          const int b = gm >> 11, nn = gm & 2047;
          const int h = gn >> 7, d = gn & 127;
          (op ? ko : qo)[((size_t)(b * 16 + h) * 2048 + nn) * 128 + d] = v;
        } else {
          const int h = gm >> 7, d = gm & 127;
          const int b = gn >> 11, nn = gn & 2047;
          vo[((size_t)(b * 16 + h) * 128 + d) * 2048 + nn] = v;
        }
      }
}

// ---------------------------------------------------------------------------
// GEMM-BT (final projection): C[m][n] = sum_k A[m][k]*B[n][k], C row-major f32.
// NT=64 tile, BK=64 + XOR involution (proven round 11): K=2048 -> 32 barrier
// pairs. LDS = 16KB A + 8KB B = 24KB.
// v2: T1 XCD swizzle on the linearized block id (512 blocks, 512%8==0):
// each XCD's blocks become 4 contiguous m-panels + all n-panels (~6MB vs
// ~20MB unswizzled working set per XCD L2).
// ---------------------------------------------------------------------------
template <int NT, typename OT>
__global__ __launch_bounds__(256)
void gemm_bt(const bf16* __restrict__ A, const bf16* __restrict__ B,
             OT* __restrict__ C, int M, int N, int K) {
  __shared__ __align__(16) bf16 As[128 * 64];
  __shared__ __align__(16) bf16 Bs[NT * 64];
  constexpr int JN = NT / 32;
  const int t = threadIdx.x;
  const int l = t & 63, w = t >> 6;
  const int q4 = l >> 4, li = l & 15;
  const int lin = blockIdx.y * gridDim.x + blockIdx.x;
  const int nwg8 = (gridDim.x * gridDim.y) >> 3;
  const int swz = (lin & 7) * nwg8 + (lin >> 3);  // XCD-contiguous remap
  const int m0 = (swz / gridDim.x) * 128;
  const int n0 = (swz % gridDim.x) * NT;
  const int wr = (w >> 1) * 64, wc = (w & 1) * (NT / 2);

  f32x4 acc[4][JN] = {};
  const int srow = t >> 3;             // row within 32-row staging round
  const int schu = t & 7;              // chunk (8 per 64-elem row)
  const int wavebase = (t & ~63) * 8;  // LDS elems, wave-uniform
  const bf16* gA = A + (size_t)m0 * K;
  const bf16* gB = B + (size_t)n0 * K;

  for (int k0 = 0; k0 < K; k0 += 64) {
#pragma unroll
    for (int p = 0; p < 4; ++p) {
      const int row = p * 32 + srow;
      const int cs = (schu ^ (row & 7)) * 8;
      async_ld16(gA + (size_t)row * K + k0 + cs, &As[p * 2048 + wavebase]);
    }
#pragma unroll
    for (int p = 0; p < NT / 32; ++p) {
      const int row = p * 32 + srow;
      const int cs = (schu ^ (row & 7)) * 8;
      async_ld16(gB + (size_t)row * K + k0 + cs, &Bs[p * 2048 + wavebase]);
    }
    __syncthreads();
#pragma unroll
    for (int kk = 0; kk < 2; ++kk) {
      bf16x8 af[4], bfr[JN];
#pragma unroll
      for (int i = 0; i < 4; ++i)
        af[i] = *(const bf16x8*)&As[(wr + i * 16 + li) * 64 +
                                    (((kk * 4 + q4) ^ (li & 7)) * 8)];
#pragma unroll
      for (int j = 0; j < JN; ++j)
        bfr[j] = *(const bf16x8*)&Bs[(wc + j * 16 + li) * 64 +
                                     (((kk * 4 + q4) ^ (li & 7)) * 8)];
#pragma unroll
      for (int i = 0; i < 4; ++i)
#pragma unroll
        for (int j = 0; j < JN; ++j)
          acc[i][j] = MFMA16(af[i], bfr[j], acc[i][j]);
    }
    __syncthreads();
  }

#pragma unroll
  for (int i = 0; i < 4; ++i)
#pragma unroll
    for (int j = 0; j < JN; ++j)
#pragma unroll
      for (int r = 0; r < 4; ++r) {
        const int gm = m0 + wr + i * 16 + q4 * 4 + r;
        const int gn = n0 + wc + j * 16 + li;
        C[(size_t)gm * N + gn] = cvt_out<OT>(acc[i][j][r]);
      }
}

// ---------------------------------------------------------------------------
// Causal flash attention, S^T formulation. (Unchanged from round 12.)
// v11: QT=64 (16q/wave), grid (32,32)=1024 blocks, K+V in LDS (64-key
// single-buffered, 16KB+16KB), bounds(256,2), setprio around QK/PV MFMA
// clusters, T13 defer-max THR=8, source-XOR staging, fused exp2, long-first
// dispatch. Structural floor ~78us: no pipe saturated (MFMA 27/VALU 31/LDS
// ~46%), TLP exhausted (occupancy 13/26/31% -> 84/79.6/101us), LDS access
// at per-bank floor. XCD locality already perfect (bid=bh+32y, 32%8==0:
// all blocks of one bh land on one XCD).
// ---------------------------------------------------------------------------
__global__ __launch_bounds__(256, 2)
void flash_attn(const bf16* __restrict__ qm, const bf16* __restrict__ km,
                const bf16* __restrict__ vtm, bf16* __restrict__ om) {
  __shared__ __align__(16) bf16 Ks[64 * 128];   // [key][d]
  __shared__ __align__(16) bf16 Vts[128 * 64];  // [d][key]

  const int t = threadIdx.x;
  const int l = t & 63, w = t >> 6;
  const int q4 = l >> 4, li = l & 15;
  const int bh = blockIdx.x;
  const int y = blockIdx.y;
  const int qt = (y < 16) ? 31 - y : y - 16;  // long blocks dispatch first
  const int qs = qt * 64;
  const size_t qkbase = (size_t)bh * 2048 * 128;
  const size_t vbase = (size_t)bh * 128 * 2048;
  const int b = bh >> 4, h = bh & 15;

  // Q fragments (B operand of S^T), 16 queries for this wave
  bf16x8 qf[4];
  {
    const bf16* Qb = qm + qkbase + (size_t)(qs + w * 16 + li) * 128;
#pragma unroll
    for (int f = 0; f < 4; ++f)
      qf[f] = *(const bf16x8*)(Qb + f * 32 + q4 * 8);
  }

  f32x4 O[8] = {};
  float mrun = NEG_BIG, lrun = 0.f;
  const int gmq = qs + w * 16 + li;  // this lane's query index

  // staging address components (per lane, constant across tiles)
  const int ksrow = t >> 4;            // K: row within 16-row group
  const int kchu = t & 15;             // K: chunk (16 per 128-elem row)
  const int vsrow = t >> 3;            // V: row within 32-row group
  const int vchu = t & 7;              // V: chunk (8 per 64-elem row)
  const int wavebase = (t & ~63) * 8;  // LDS elems, wave-uniform

  const int nt = qt + 1;  // number of 64-key tiles

  for (int j = 0; j < nt; ++j) {
    const int kb = j * 64;
    // stage K (64 keys x 128 d) and Vt (128 d x 64 keys) via async DMA,
    // source-swizzled: lane loads global chunk (chu)^(row&7), lands at
    // linear LDS position (row, chu).
#pragma unroll
    for (int p = 0; p < 4; ++p) {
      const int kr = p * 16 + ksrow;
      async_ld16(km + qkbase + (size_t)(kb + kr) * 128 + (size_t)((kchu ^ (kr & 7)) * 8),
                 &Ks[p * 2048 + wavebase]);
      const int vr = p * 32 + vsrow;
      async_ld16(vtm + vbase + (size_t)vr * 2048 + kb + (size_t)((vchu ^ (vr & 7)) * 8),
                 &Vts[p * 2048 + wavebase]);
    }
    __syncthreads();

    const bool msk = (j == qt);  // only the diagonal tile masks

    // S^T = K Q^T : S[jk] reg r = raw score(key = kb+jk*16+q4*4+r, query li)
    f32x4 S[4];
    __builtin_amdgcn_s_setprio(1);
#pragma unroll
    for (int jk = 0; jk < 4; ++jk) {
      const int krow = jk * 16 + li;
      bf16x8 kf[4];
#pragma unroll
      for (int f = 0; f < 4; ++f)
        kf[f] = *(const bf16x8*)&Ks[krow * 128 + (((f * 4 + q4) ^ (li & 7)) * 8)];
      f32x4 s = {0.f, 0.f, 0.f, 0.f};
#pragma unroll
      for (int f = 0; f < 4; ++f) s = MFMA16(kf[f], qf[f], s);
      S[jk] = s;
    }
    __builtin_amdgcn_s_setprio(0);

    if (msk) {
#pragma unroll
      for (int jk = 0; jk < 4; ++jk)
#pragma unroll
        for (int r = 0; r < 4; ++r)
          if ((kb + jk * 16 + q4 * 4 + r) > gmq) S[jk][r] = NEG_BIG;
    }

    // tile max (per query li, uniform across the 4 q4 lanes)
    float mx = NEG_BIG;
#pragma unroll
    for (int jk = 0; jk < 4; ++jk)
      mx = fmaxf(mx, fmaxf(fmaxf(S[jk][0], S[jk][1]), fmaxf(S[jk][2], S[jk][3])));
    mx = fmaxf(mx, __shfl_xor(mx, 16));
    mx = fmaxf(mx, __shfl_xor(mx, 32));

    // T13 defer-max: keep old running max unless growth > 8 exp2-arg units
    // (then P <= 2^8 = 256; bf16/f32-safe). Wave-uniform decision BEFORE e.
    const float mold = mrun;
    const bool keep = __all((mx - mrun) * K2SCALE <= 8.0f);
    if (!keep) mrun = fmaxf(mrun, mx);
    const float nmk = mrun * K2SCALE;

    bf16x4 pb[4];
    float rs = 0.f;
#pragma unroll
    for (int jk = 0; jk < 4; ++jk) {
      float e[4];
#pragma unroll
      for (int r = 0; r < 4; ++r) {
        e[r] = EXP2F(__builtin_fmaf(S[jk][r], K2SCALE, -nmk));
        pb[jk][r] = f2bf(e[r]);
      }
      rs += (e[0] + e[1]) + (e[2] + e[3]);
    }
    rs += __shfl_xor(rs, 16);
    rs += __shfl_xor(rs, 32);

    if (keep) {  // running max unchanged: alpha == 1 everywhere
      lrun += rs;
    } else {
      const float alpha = EXP2F((mold - mrun) * K2SCALE);
      lrun = lrun * alpha + rs;
#pragma unroll
      for (int dt = 0; dt < 8; ++dt) O[dt] *= alpha;
    }

    // O^T += V^T P^T : V^T from LDS (swizzled layout)
    __builtin_amdgcn_s_setprio(1);
#pragma unroll
    for (int dt = 0; dt < 8; ++dt)
#pragma unroll
      for (int kc = 0; kc < 4; ++kc) {
        const int gc = kc * 2 + (q4 >> 1);  // key-chunk within 64-key tile
        const bf16x4 va = *(const bf16x4*)&Vts[(dt * 16 + li) * 64 +
                                               ((gc ^ (li & 7)) * 8) +
                                               (q4 & 1) * 4];
        O[dt] = pv_mfma(va, pb[kc], O[dt]);
      }
    __builtin_amdgcn_s_setprio(0);
    __syncthreads();
  }

  // epilogue: normalize, write om[query][h*128+d], d = dt*16+q4*4+r
  {
    const float inv = 1.0f / lrun;
    const size_t orow = (size_t)(b * 2048 + qs + w * 16 + li) * 2048 + h * 128;
#pragma unroll
    for (int dt = 0; dt < 8; ++dt) {
      bf16x4 o4;
#pragma unroll
      for (int r = 0; r < 4; ++r) o4[r] = f2bf(O[dt][r] * inv);
      *(bf16x4*)&om[orow + dt * 16 + q4 * 4] = o4;
    }
  }
}

// ---------------------------------------------------------------------------
extern "C" void kernel_launch(void* const* d_in, const int* in_sizes, int n_in,
                              void* d_out, int out_size, void* d_ws, size_t ws_size,
                              hipStream_t stream) {
  const float* x = (const float*)d_in[0];
  const float* Wq = (const float*)d_in[1];
  const float* Wk = (const float*)d_in[2];
  const float* Wv = (const float*)d_in[3];
  const float* Wo = (const float*)d_in[4];
  float* out = (float*)d_out;

  // Workspace (bf16 elems), 36M = 72 MB:
  //   [0,4M) xb | [4M,6M) wTq | [6M,8M) wTk | [8M,10M) wTv | [10M,12M) woT
  //   [12M,20M) q_ws | [20M,28M) k_ws | [28M,36M) vt_ws
  //   at_ws = [2M,10M) (aliases xb-upper + wTq/k/v; dead before flash writes)
  bf16* ws = (bf16*)d_ws;
  const size_t MEG = 1u << 20;
  bf16* xb = ws;
  bf16* wTq = ws + 4 * MEG;
  bf16* wTk = ws + 6 * MEG;
  bf16* wTv = ws + 8 * MEG;
  bf16* woT = ws + 10 * MEG;
  bf16* at_ws = ws + 2 * MEG;
  bf16* q_ws = ws + 12 * MEG;
  bf16* k_ws = ws + 20 * MEG;
  bf16* vt_ws = ws + 28 * MEG;

  const dim3 blk(256);

  prep<<<dim3(12288), blk, 0, stream>>>(x, Wq, Wk, Wv, Wo, xb, wTq, wTk, wTv, woT);
  gemm_qkv<<<dim3(512, 3), blk, 0, stream>>>(xb, wTq, wTk, wTv, q_ws, k_ws, vt_ws);
  flash_attn<<<dim3(32, 32), blk, 0, stream>>>(q_ws, k_ws, vt_ws, at_ws);
  gemm_bt<64, float><<<dim3(16, 32), blk, 0, stream>>>(at_ws, woT, out, 4096, 1024, 2048);
}